// Round 14
// baseline (222.700 us; speedup 1.0000x reference)
//
#include <hip/hip_runtime.h>
#include <hip/hip_bf16.h>
#include <cstddef>
#include <math.h>

#define NTOK 1200          // B*NQ = 4*300
#define LTOT_C 17821
#define MVAL 71284         // B*LTOT
#define STOK (NTOK * 256)  // 307200

typedef __attribute__((ext_vector_type(8))) short bhalf8;
typedef __attribute__((ext_vector_type(4))) float f32x4;

static __device__ __forceinline__ short f2bf(float f) {
    unsigned u = __builtin_bit_cast(unsigned, f);
    u += 0x7fffu + ((u >> 16) & 1u);   // RNE
    return (short)(u >> 16);
}
static __device__ __forceinline__ float bf2f(short s) {
    unsigned u = ((unsigned)(unsigned short)s) << 16;
    return __builtin_bit_cast(float, u);
}
static __device__ __forceinline__ bhalf8 cvt8(float4 a, float4 b) {
    bhalf8 h;
    h[0] = f2bf(a.x); h[1] = f2bf(a.y); h[2] = f2bf(a.z); h[3] = f2bf(a.w);
    h[4] = f2bf(b.x); h[5] = f2bf(b.y); h[6] = f2bf(b.z); h[7] = f2bf(b.w);
    return h;
}
// async global -> LDS, 16B per lane; lds dest is wave-uniform base + lane*16
static __device__ __forceinline__ void gload_lds16(const void* g, void* l) {
    __builtin_amdgcn_global_load_lds(
        (const __attribute__((address_space(1))) void*)g,
        (__attribute__((address_space(3))) void*)l, 16, 0, 0);
}

// ---------------- weight convert fp32 -> bf16 (10 tasks) ----------------
struct WcvtArgs { const float* s[10]; short* d[10]; int n[10]; };
__global__ __launch_bounds__(256) void wcvt(WcvtArgs a) {
    const int ti = blockIdx.y;
    const float* s = a.s[ti];
    short* d = a.d[ti];
    const int n = a.n[ti];
    for (int base = (blockIdx.x * 256 + threadIdx.x) * 8; base < n; base += gridDim.x * 256 * 8) {
        const float4 f0 = *reinterpret_cast<const float4*>(s + base);
        const float4 f1 = *reinterpret_cast<const float4*>(s + base + 4);
        *reinterpret_cast<bhalf8*>(d + base) = cvt8(f0, f1);
    }
}

// ---------------- activation prep ----------------
__global__ __launch_bounds__(256) void prep_act(
    const float* __restrict__ tgt0, const float* __restrict__ tgt1,
    const float* __restrict__ pos0, const float* __restrict__ pos1,
    short* __restrict__ qb_bf, short* __restrict__ tgtb,
    const float* __restrict__ off_b, const float* __restrict__ aw_b,
    float* __restrict__ baw)
{
    const int z = blockIdx.y;
    if (blockIdx.x == 0 && z == 0) {
        for (int i = threadIdx.x; i < 768; i += 256) {
            const int zz = i / 384, j = i - zz * 384;
            baw[i] = (j < 256) ? off_b[zz * 256 + j] : aw_b[zz * 128 + (j - 256)];
        }
    }
    const float* tg = z ? tgt1 : tgt0;
    const float* ps = z ? pos1 : pos0;
    const int base = (blockIdx.x * 256 + threadIdx.x) * 8;
    if (base >= STOK) return;
    const float4 t0 = *reinterpret_cast<const float4*>(tg + base);
    const float4 t1 = *reinterpret_cast<const float4*>(tg + base + 4);
    const float4 p0 = *reinterpret_cast<const float4*>(ps + base);
    const float4 p1 = *reinterpret_cast<const float4*>(ps + base + 4);
    float4 s0 = make_float4(t0.x + p0.x, t0.y + p0.y, t0.z + p0.z, t0.w + p0.w);
    float4 s1 = make_float4(t1.x + p1.x, t1.y + p1.y, t1.z + p1.z, t1.w + p1.w);
    *reinterpret_cast<bhalf8*>(qb_bf + (size_t)z * STOK + base) = cvt8(s0, s1);
    *reinterpret_cast<bhalf8*>(tgtb + (size_t)z * STOK + base) = cvt8(t0, t1);
}

// ---------------- value projection: r12 pipeline, BN=64, 24 KB LDS (6 blocks/CU) --------
// Tile 64(M) x 64(N), 4 waves (2x2, each 32x32), BK=64, NK=4.
// A fp32->reg (issued early) -> bf16 ds_write between two barriers (single 8 KB buffer);
// W async global_load_lds double-buffered (2 x 8 KB).
// Grid: 1D 8912 = 8*1114, bijective XCD chunking; widx -> (x 0..3, y 0..1113, z 0..1).
__global__ __launch_bounds__(256) void gemm_val(
    const float* __restrict__ A0, const float* __restrict__ A1,
    const short* __restrict__ Wbf, const float* __restrict__ bias,
    short* __restrict__ C)
{
    __shared__ alignas(16) short As[64 * 64];       // 8 KB
    __shared__ alignas(16) short Bs[2][64 * 64];    // 2 x 8 KB
    const int i = blockIdx.x;                       // 8912 = 8 * 1114
    const int widx = (i & 7) * 1114 + (i >> 3);     // bijective XCD chunking
    const int x = widx & 3;
    const int yz = widx >> 2;                       // 0..2227
    const int z = yz / 1114;
    const int y = yz - z * 1114;
    const float* A = z ? A1 : A0;
    const short* W = Wbf + (size_t)z * 65536;
    const float* bz = bias + z * 256;
    short* Cz = C + (size_t)z * MVAL * 256;
    const int t = threadIdx.x;
    const int wave = t >> 6, lane = t & 63;
    const int l15 = lane & 15, l4 = lane >> 4;
    const int wr = wave >> 1, wc = wave & 1;
    const int bm = y * 64, bn = x * 64;
    f32x4 acc[2][2] = {};

    const int nr8 = lane >> 3, q8 = lane & 7;
    auto stageW = [&](int k0, int buf) {
        #pragma unroll
        for (int ii = 0; ii < 2; ++ii) {
            const int c = wave * 2 + ii;
            const int n = c * 8 + nr8;
            gload_lds16(W + (size_t)(bn + n) * 256 + k0 + ((q8 ^ nr8) << 3),
                        (char*)&Bs[buf][0] + c * 1024);
        }
    };
    float4 paf[2][2];
    auto issueA = [&](int k0) {
        #pragma unroll
        for (int ii = 0; ii < 2; ++ii) {
            const int G = t + ii * 256;
            const int m = G >> 3, g = G & 7;
            const int row = min(bm + m, MVAL - 1);
            const float* s = A + (size_t)row * 256 + k0 + g * 8;
            paf[ii][0] = *reinterpret_cast<const float4*>(s);
            paf[ii][1] = *reinterpret_cast<const float4*>(s + 4);
        }
    };
    auto commitA = [&]() {
        #pragma unroll
        for (int ii = 0; ii < 2; ++ii) {
            const int G = t + ii * 256;
            const int m = G >> 3, g = G & 7;
            *reinterpret_cast<bhalf8*>(&As[m * 64 + ((g ^ (m & 7)) << 3)]) =
                cvt8(paf[ii][0], paf[ii][1]);
        }
    };
    auto compute = [&](int wbuf) {
        #pragma unroll
        for (int kf = 0; kf < 2; ++kf) {
            bhalf8 af[2], bfv[2];
            #pragma unroll
            for (int mf = 0; mf < 2; ++mf) {
                const int m = wr * 32 + (mf << 4) + l15;
                const int g = ((kf << 2) + l4) ^ (m & 7);
                af[mf] = *reinterpret_cast<const bhalf8*>(&As[m * 64 + (g << 3)]);
            }
            #pragma unroll
            for (int nf = 0; nf < 2; ++nf) {
                const int n = wc * 32 + (nf << 4) + l15;
                const int g = ((kf << 2) + l4) ^ (n & 7);
                bfv[nf] = *reinterpret_cast<const bhalf8*>(&Bs[wbuf][n * 64 + (g << 3)]);
            }
            #pragma unroll
            for (int mf = 0; mf < 2; ++mf)
                #pragma unroll
                for (int nf = 0; nf < 2; ++nf)
                    acc[mf][nf] = __builtin_amdgcn_mfma_f32_16x16x32_bf16(
                        af[mf], bfv[nf], acc[mf][nf], 0, 0, 0);
        }
    };

    issueA(0);
    stageW(0, 0);
    commitA();
    __syncthreads();
    #pragma unroll
    for (int ks = 0; ks < 4; ++ks) {
        const int cur = ks & 1, nxt = cur ^ 1;
        if (ks + 1 < 4) {
            issueA((ks + 1) << 6);
            stageW((ks + 1) << 6, nxt);
        }
        compute(cur);
        if (ks + 1 < 4) {
            __syncthreads();
            commitA();
            __syncthreads();
        }
    }

    float br[2];
    #pragma unroll
    for (int nf = 0; nf < 2; ++nf) br[nf] = bz[bn + wc * 32 + (nf << 4) + l15];
    #pragma unroll
    for (int mf = 0; mf < 2; ++mf) {
        #pragma unroll
        for (int j = 0; j < 4; ++j) {
            const int row = bm + wr * 32 + (mf << 4) + (l4 << 2) + j;
            if (row >= MVAL) continue;
            #pragma unroll
            for (int nf = 0; nf < 2; ++nf)
                Cz[(size_t)row * 256 + bn + wc * 32 + (nf << 4) + l15] =
                    f2bf(acc[mf][nf][j] + br[nf]);
        }
    }
}

// ---------------- unified bf16 MFMA GEMM (bf16 A): async gload_lds, dbuf ----------------
template<bool HASRES, bool RELU, bool OUT_BF16, int BM, int NK>
__global__ __launch_bounds__(256) void gemm_bf16(
    const short* __restrict__ Av, const short* __restrict__ Av2, int xsplit,
    size_t aStrideZ, int lda,
    const short* __restrict__ Wv, size_t wStrideZ, int ldw,
    const float* __restrict__ bias, size_t biasStrideZ,
    const float* __restrict__ Res0, const float* __restrict__ Res1, int ldr,
    void* __restrict__ Cv, size_t cStrideZ, int ldc,
    int M)
{
    constexpr int MFR = BM / 32;
    constexpr int ACW = BM / 32;
    __shared__ alignas(16) short As[2][BM * 64];
    __shared__ alignas(16) short Bs[2][128 * 64];
    const int z = blockIdx.z;
    const short* Abase = (Av2 != nullptr && (int)blockIdx.x >= xsplit) ? Av2 : Av;
    const short* W = Wv + (size_t)z * wStrideZ;
    const float* bz = bias + (size_t)z * biasStrideZ;
    const int t = threadIdx.x;
    const int wave = t >> 6, lane = t & 63;
    const int l15 = lane & 15, l4 = lane >> 4;
    const int wr = wave >> 1, wc = wave & 1;
    const int bm = blockIdx.y * BM, bn = blockIdx.x * 128;
    f32x4 acc[MFR][4] = {};

    const int nr8 = lane >> 3, q8 = lane & 7;
    auto stageW = [&](int k0, int buf) {
        #pragma unroll
        for (int i = 0; i < 4; ++i) {
            const int c = wave * 4 + i;
            const int n = c * 8 + nr8;
            gload_lds16(W + (size_t)(bn + n) * ldw + k0 + ((q8 ^ nr8) << 3),
                        (char*)&Bs[buf][0] + c * 1024);
        }
    };
    auto stageA = [&](int k0, int buf) {
        #pragma unroll
        for (int i = 0; i < ACW; ++i) {
            const int c = wave * ACW + i;
            const int m = c * 8 + nr8;
            const int row = min(bm + m, M - 1);
            gload_lds16(Abase + (size_t)z * aStrideZ + (size_t)row * lda + k0 + ((q8 ^ (m & 7)) << 3),
                        (char*)&As[buf][0] + c * 1024);
        }
    };
    auto compute = [&](int buf) {
        #pragma unroll
        for (int kf = 0; kf < 2; ++kf) {
            bhalf8 af[MFR], bfv[4];
            #pragma unroll
            for (int mf = 0; mf < MFR; ++mf) {
                const int m = wr * (BM / 2) + (mf << 4) + l15;
                const int g = ((kf << 2) + l4) ^ (m & 7);
                af[mf] = *reinterpret_cast<const bhalf8*>(&As[buf][m * 64 + (g << 3)]);
            }
            #pragma unroll
            for (int nf = 0; nf < 4; ++nf) {
                const int n = (wc << 6) + (nf << 4) + l15;
                const int g = ((kf << 2) + l4) ^ (n & 7);
                bfv[nf] = *reinterpret_cast<const bhalf8*>(&Bs[buf][n * 64 + (g << 3)]);
            }
            #pragma unroll
            for (int mf = 0; mf < MFR; ++mf)
                #pragma unroll
                for (int nf = 0; nf < 4; ++nf)
                    acc[mf][nf] = __builtin_amdgcn_mfma_f32_16x16x32_bf16(
                        af[mf], bfv[nf], acc[mf][nf], 0, 0, 0);
        }
    };

    stageA(0, 0);
    stageW(0, 0);
    __syncthreads();
    #pragma unroll
    for (int ks = 0; ks < NK; ++ks) {
        const int cur = ks & 1, nxt = cur ^ 1;
        if (ks + 1 < NK) {
            stageA((ks + 1) << 6, nxt);
            stageW((ks + 1) << 6, nxt);
        }
        compute(cur);
        __syncthreads();
    }

    const float* Rz = HASRES ? (z ? Res1 : Res0) : nullptr;
    float br[4];
    #pragma unroll
    for (int nf = 0; nf < 4; ++nf) br[nf] = bz[bn + (wc << 6) + (nf << 4) + l15];
    #pragma unroll
    for (int mf = 0; mf < MFR; ++mf) {
        #pragma unroll
        for (int j = 0; j < 4; ++j) {
            const int row = bm + wr * (BM / 2) + (mf << 4) + (l4 << 2) + j;
            if (row >= M) continue;
            const int colbase = bn + (wc << 6);
            #pragma unroll
            for (int nf = 0; nf < 4; ++nf) {
                const int col = colbase + (nf << 4) + l15;
                float v = acc[mf][nf][j] + br[nf];
                if (HASRES) v += Rz[(size_t)row * ldr + col];
                if (RELU) v = fmaxf(v, 0.f);
                if (OUT_BF16)
                    ((short*)Cv + (size_t)z * cStrideZ)[(size_t)row * ldc + col] = f2bf(v);
                else
                    ((float*)Cv + (size_t)z * cStrideZ)[(size_t)row * ldc + col] = v;
            }
        }
    }
}

// ---------------- full-N GEMM + fused row-LayerNorm epilogue ----------------
// Block = 64 rows x 256 cols; 4 waves split N (wave w: cols w*64..w*64+63).
// MODE 0 (outproj+norm2): y = LN(A@W + b + tgt);  qc_bf = bf16(y+pos); tgt2T = y (z==1)
// MODE 1 (ffn2+norm3):    y = LN(A@W + b + res) -> out0/out1 fp32
template<int NK, int MODE>
__global__ __launch_bounds__(256) void gemm_ln(
    const short* __restrict__ Av, size_t aStrideZ, int lda,
    const short* __restrict__ Wv, size_t wStrideZ,
    const float* __restrict__ bias, size_t biasStrideZ,
    const float* __restrict__ Res0, const float* __restrict__ Res1,
    const float* __restrict__ ln_w, const float* __restrict__ ln_b,
    const float* __restrict__ pos0, const float* __restrict__ pos1,
    short* __restrict__ qc_bf, float* __restrict__ tgt2T,
    float* __restrict__ out0, float* __restrict__ out1,
    int M)
{
    __shared__ alignas(16) short As[2][64 * 64];     // 16 KB
    __shared__ alignas(16) short Bs[2][256 * 64];    // 64 KB
    __shared__ float red[2][4][64];
    const int z = blockIdx.z;
    const short* W = Wv + (size_t)z * wStrideZ;
    const float* bz = bias + (size_t)z * biasStrideZ;
    const float* Rz = z ? Res1 : Res0;
    const int li = z * 3 + (MODE == 0 ? 1 : 2);
    const int t = threadIdx.x;
    const int wave = t >> 6, lane = t & 63;
    const int l15 = lane & 15, l4 = lane >> 4;
    const int bm = blockIdx.y * 64;
    f32x4 acc[4][4] = {};

    const int nr8 = lane >> 3, q8 = lane & 7;
    auto stageW = [&](int k0, int buf) {
        #pragma unroll
        for (int i = 0; i < 8; ++i) {
            const int c = wave * 8 + i;
            const int n = c * 8 + nr8;
            gload_lds16(W + (size_t)n * lda + k0 + ((q8 ^ nr8) << 3),
                        (char*)&Bs[buf][0] + c * 1024);
        }
    };
    auto stageA = [&](int k0, int buf) {
        #pragma unroll
        for (int i = 0; i < 2; ++i) {
            const int c = wave * 2 + i;
            const int m = c * 8 + nr8;
            const int row = min(bm + m, M - 1);
            gload_lds16(Av + (size_t)z * aStrideZ + (size_t)row * lda + k0 + ((q8 ^ (m & 7)) << 3),
                        (char*)&As[buf][0] + c * 1024);
        }
    };
    auto compute = [&](int buf) {
        #pragma unroll
        for (int kf = 0; kf < 2; ++kf) {
            bhalf8 af[4], bfv[4];
            #pragma unroll
            for (int mf = 0; mf < 4; ++mf) {
                const int m = (mf << 4) + l15;
                const int g = ((kf << 2) + l4) ^ (m & 7);
                af[mf] = *reinterpret_cast<const bhalf8*>(&As[buf][m * 64 + (g << 3)]);
            }
            #pragma unroll
            for (int nf = 0; nf < 4; ++nf) {
                const int n = (wave << 6) + (nf << 4) + l15;
                const int g = ((kf << 2) + l4) ^ (n & 7);
                bfv[nf] = *reinterpret_cast<const bhalf8*>(&Bs[buf][n * 64 + (g << 3)]);
            }
            #pragma unroll
            for (int mf = 0; mf < 4; ++mf)
                #pragma unroll
                for (int nf = 0; nf < 4; ++nf)
                    acc[mf][nf] = __builtin_amdgcn_mfma_f32_16x16x32_bf16(
                        af[mf], bfv[nf], acc[mf][nf], 0, 0, 0);
        }
    };

    stageA(0, 0);
    stageW(0, 0);
    __syncthreads();
    #pragma unroll
    for (int ks = 0; ks < NK; ++ks) {
        const int cur = ks & 1, nxt = cur ^ 1;
        if (ks + 1 < NK) {
            stageA((ks + 1) << 6, nxt);
            stageW((ks + 1) << 6, nxt);
        }
        compute(cur);
        __syncthreads();
    }

    // v = acc + bias + residual
    float br[4];
    #pragma unroll
    for (int nf = 0; nf < 4; ++nf) br[nf] = bz[(wave << 6) + (nf << 4) + l15];
    #pragma unroll
    for (int mf = 0; mf < 4; ++mf) {
        #pragma unroll
        for (int j = 0; j < 4; ++j) {
            const int row = bm + (mf << 4) + (l4 << 2) + j;
            const int rr = min(row, M - 1);
            #pragma unroll
            for (int nf = 0; nf < 4; ++nf) {
                const int col = (wave << 6) + (nf << 4) + l15;
                acc[mf][nf][j] += br[nf] + Rz[(size_t)rr * 256 + col];
            }
        }
    }
    // per-row stats: in-lane over nf, shfl over 16-lane group, LDS across waves
    #pragma unroll
    for (int mf = 0; mf < 4; ++mf) {
        #pragma unroll
        for (int j = 0; j < 4; ++j) {
            float s = 0.f, q = 0.f;
            #pragma unroll
            for (int nf = 0; nf < 4; ++nf) {
                const float v = acc[mf][nf][j];
                s += v; q += v * v;
            }
            #pragma unroll
            for (int o = 1; o < 16; o <<= 1) {
                s += __shfl_xor(s, o);
                q += __shfl_xor(q, o);
            }
            if (l15 == 0) {
                const int rl = (mf << 4) + (l4 << 2) + j;
                red[0][wave][rl] = s;
                red[1][wave][rl] = q;
            }
        }
    }
    __syncthreads();
    const float* posz = (MODE == 0) ? (z ? pos1 : pos0) : nullptr;
    #pragma unroll
    for (int mf = 0; mf < 4; ++mf) {
        #pragma unroll
        for (int j = 0; j < 4; ++j) {
            const int rl = (mf << 4) + (l4 << 2) + j;
            const int row = bm + rl;
            if (row >= M) continue;
            const float mean = (red[0][0][rl] + red[0][1][rl] + red[0][2][rl] + red[0][3][rl]) * (1.f / 256.f);
            const float ex2  = (red[1][0][rl] + red[1][1][rl] + red[1][2][rl] + red[1][3][rl]) * (1.f / 256.f);
            const float rstd = rsqrtf(ex2 - mean * mean + 1e-5f);
            #pragma unroll
            for (int nf = 0; nf < 4; ++nf) {
                const int col = (wave << 6) + (nf << 4) + l15;
                const float yv = (acc[mf][nf][j] - mean) * rstd * ln_w[li * 256 + col] + ln_b[li * 256 + col];
                if (MODE == 0) {
                    qc_bf[(size_t)z * STOK + (size_t)row * 256 + col] = f2bf(yv + posz[(size_t)row * 256 + col]);
                    if (z == 1) tgt2T[(size_t)row * 256 + col] = yv;
                } else {
                    (z ? out1 : out0)[(size_t)row * 256 + col] = yv;
                }
            }
        }
    }
}

// ---------------- self-attention: key-parallel online softmax, bf16 out ----------------
__global__ __launch_bounds__(256) void attn2_kernel(
    const float* __restrict__ qkv_base, short* __restrict__ out_base)
{
    const float scale = 0.17677669529663687f;  // 1/sqrt(32)
    const float* qkv = qkv_base + (size_t)blockIdx.z * 921600;
    short* outp = out_base + (size_t)blockIdx.z * STOK;
    const int b = blockIdx.y >> 3, h = blockIdx.y & 7;
    const int t = threadIdx.x;
    const int ql = t & 31;
    const int kg = t >> 5;
    const int q = blockIdx.x * 32 + ql;
    const bool act = q < 300;
    const float* base = qkv + (size_t)b * 300 * 768;

    float qreg[32];
    if (act) {
        const float4* qp = reinterpret_cast<const float4*>(base + (size_t)q * 768 + h * 32);
        #pragma unroll
        for (int d4 = 0; d4 < 8; ++d4) {
            const float4 v = qp[d4];
            qreg[d4 * 4 + 0] = v.x; qreg[d4 * 4 + 1] = v.y;
            qreg[d4 * 4 + 2] = v.z; qreg[d4 * 4 + 3] = v.w;
        }
    }
    __shared__ float Ks[64][32];
    __shared__ float Vs[64][32];
    float m = -1e30f, l = 0.f, o[32];
    #pragma unroll
    for (int d = 0; d < 32; ++d) o[d] = 0.f;

    for (int k0 = 0; k0 < 300; k0 += 64) {
        const int cnt = min(64, 300 - k0);
        __syncthreads();
        for (int i = t; i < cnt * 32; i += 256) {
            const int kr = i >> 5, d = i & 31;
            Ks[kr][d] = base[(size_t)(k0 + kr) * 768 + 256 + h * 32 + d];
            Vs[kr][d] = base[(size_t)(k0 + kr) * 768 + 512 + h * 32 + d];
        }
        __syncthreads();
        if (act) {
            for (int kk = kg; kk < cnt; kk += 8) {
                const float4* krow = reinterpret_cast<const float4*>(&Ks[kk][0]);
                float s = 0.f;
                #pragma unroll
                for (int d4 = 0; d4 < 8; ++d4) {
                    const float4 kv = krow[d4];
                    s += qreg[d4 * 4 + 0] * kv.x + qreg[d4 * 4 + 1] * kv.y
                       + qreg[d4 * 4 + 2] * kv.z + qreg[d4 * 4 + 3] * kv.w;
                }
                s *= scale;
                const float4* vrow = reinterpret_cast<const float4*>(&Vs[kk][0]);
                if (s <= m) {
                    const float e = __expf(s - m);
                    l += e;
                    #pragma unroll
                    for (int d4 = 0; d4 < 8; ++d4) {
                        const float4 vv = vrow[d4];
                        o[d4 * 4 + 0] += e * vv.x; o[d4 * 4 + 1] += e * vv.y;
                        o[d4 * 4 + 2] += e * vv.z; o[d4 * 4 + 3] += e * vv.w;
                    }
                } else {
                    const float c = __expf(m - s);
                    l = l * c + 1.f;
                    #pragma unroll
                    for (int d4 = 0; d4 < 8; ++d4) {
                        const float4 vv = vrow[d4];
                        o[d4 * 4 + 0] = o[d4 * 4 + 0] * c + vv.x;
                        o[d4 * 4 + 1] = o[d4 * 4 + 1] * c + vv.y;
                        o[d4 * 4 + 2] = o[d4 * 4 + 2] * c + vv.z;
                        o[d4 * 4 + 3] = o[d4 * 4 + 3] * c + vv.w;
                    }
                    m = s;
                }
            }
        }
    }
    __shared__ float pm[32][8];
    __shared__ float pl[32][8];
    __shared__ float po[8][32][33];
    pm[ql][kg] = m; pl[ql][kg] = l;
    #pragma unroll
    for (int d = 0; d < 32; ++d) po[kg][d][ql] = o[d];
    __syncthreads();
    if (kg == 0) {
        float M = pm[ql][0];
        #pragma unroll
        for (int i = 1; i < 8; ++i) M = fmaxf(M, pm[ql][i]);
        float L = 0.f;
        #pragma unroll
        for (int i = 0; i < 8; ++i) L += pl[ql][i] * __expf(pm[ql][i] - M);
        const float invL = 1.f / L;
        #pragma unroll
        for (int i = 0; i < 8; ++i) pm[ql][i] = __expf(pm[ql][i] - M) * invL;
    }
    __syncthreads();
    if (act) {
        #pragma unroll
        for (int dd = 0; dd < 4; ++dd) {
            const int d = kg * 4 + dd;
            float v = 0.f;
            #pragma unroll
            for (int i = 0; i < 8; ++i) v += pm[ql][i] * po[i][d][ql];
            outp[((size_t)b * 300 + q) * 256 + h * 32 + d] = f2bf(v);
        }
    }
}

// ---------------- LN block-reduce body (for ln1 only) ----------------
#define LN_BODY(vexpr, widx)                                                  \
    const int row = blockIdx.x, t = threadIdx.x, z = blockIdx.y;              \
    (void)z;                                                                  \
    const int i = row * 256 + t;                                              \
    const float v = (vexpr);                                                  \
    __shared__ float r1[4], r2[4];                                            \
    float s = v;                                                              \
    _Pragma("unroll")                                                         \
    for (int o = 32; o; o >>= 1) s += __shfl_xor(s, o);                       \
    if ((t & 63) == 0) r1[t >> 6] = s;                                        \
    __syncthreads();                                                          \
    const float mean = (r1[0] + r1[1] + r1[2] + r1[3]) * (1.f / 256.f);       \
    const float dd = v - mean;                                                \
    float sq = dd * dd;                                                       \
    _Pragma("unroll")                                                         \
    for (int o = 32; o; o >>= 1) sq += __shfl_xor(sq, o);                     \
    if ((t & 63) == 0) r2[t >> 6] = sq;                                       \
    __syncthreads();                                                          \
    const float var = (r2[0] + r2[1] + r2[2] + r2[3]) * (1.f / 256.f);        \
    const float y = dd * rsqrtf(var + 1e-5f) * ln_w[(widx) * 256 + t]         \
                    + ln_b[(widx) * 256 + t];

__global__ __launch_bounds__(256) void ln1_fused(
    const float* __restrict__ tgt2T, const float* __restrict__ out2,
    const float* __restrict__ out3, const float* __restrict__ ln_w,
    const float* __restrict__ ln_b, short* __restrict__ ln1b,
    float* __restrict__ ln1f)
{
    LN_BODY(tgt2T[row * 256 + t] + out2[row * 256 + t] + (z ? out3[row * 256 + t] : 0.f), z * 3 + 0)
    ln1b[(size_t)z * STOK + i] = f2bf(y);
    ln1f[(size_t)z * STOK + i] = y;
}

// ---------------- deformable sampling: short4 gathers, wave=(q, head-half) ----------------
__global__ __launch_bounds__(256) void sample_kernel(
    const short* __restrict__ valb, const float* __restrict__ oaw,
    const float* __restrict__ ref0, const float* __restrict__ ref1,
    short* __restrict__ out)
{
    const int HL[4] = {100, 50, 25, 13};
    const int WL[4] = {134, 67, 34, 17};
    const int ST[4] = {0, 13400, 16750, 17600};
    const int z = blockIdx.y;
    const int t = threadIdx.x;
    const int wave = t >> 6, lane = t & 63;
    const int qi = wave >> 1, hh = wave & 1;
    const int pp = lane >> 5, h4 = (lane >> 3) & 3, dl = lane & 7;
    const int h = hh * 4 + h4;
    const int bq = blockIdx.x * 2 + qi;
    const int b = bq / 300;
    const float* op = oaw + ((size_t)z * NTOK + bq) * 384;
    const float* offp = op + h * 32;
    const float* awp  = op + 256 + h * 16;
    const float* refp = (z ? ref1 : ref0) + (size_t)bq * 8;
    const short* vb = valb + (size_t)z * MVAL * 256 + (size_t)b * LTOT_C * 256;
    const int co = h * 32 + dl * 4;

    float w16[16];
    float mx = -1e30f;
    #pragma unroll
    for (int i = 0; i < 16; ++i) { w16[i] = awp[i]; mx = fmaxf(mx, w16[i]); }
    float ssum = 0.f;
    #pragma unroll
    for (int i = 0; i < 16; ++i) { w16[i] = __expf(w16[i] - mx); ssum += w16[i]; }
    const float sinv = 1.f / ssum;

    float a0 = 0.f, a1 = 0.f, a2 = 0.f, a3 = 0.f;
#define TAP(cond, ridx, wv)                                                   \
    if (cond) {                                                               \
        const short4 sv = *reinterpret_cast<const short4*>(                   \
            vb + (size_t)(ridx) * 256 + co);                                  \
        a0 += (wv) * bf2f(sv.x); a1 += (wv) * bf2f(sv.y);                     \
        a2 += (wv) * bf2f(sv.z); a3 += (wv) * bf2f(sv.w);                     \
    }
    #pragma unroll
    for (int l = 0; l < 4; ++l) {
        const int Wl = WL[l], Hl = HL[l];
        const float rx = refp[l * 2] * (float)Wl - 0.5f;
        const float ry = refp[l * 2 + 1] * (float)Hl - 0.5f;
        #pragma unroll
        for (int j = 0; j < 2; ++j) {
            const int p = pp * 2 + j;
            const float px = rx + offp[(l * 4 + p) * 2];
            const float py = ry + offp[(l * 4 + p) * 2 + 1];
            const float wgt = w16[l * 4 + p] * sinv;
            const float x0f = floorf(px), y0f = floorf(py);
            const float wx = px - x0f, wy = py - y0f;
            const int x0 = (int)x0f, y0 = (int)y0f;
            const bool xa = (x0 >= 0) & (x0 < Wl);
            const bool xb = (x0 >= -1) & (x0 < Wl - 1);
            const bool ya = (y0 >= 0) & (y0 < Hl);
            const bool yb = (y0 >= -1) & (y0 < Hl - 1);
            const int rbase = ST[l] + y0 * Wl + x0;
            const float w00 = wgt * (1.f - wx) * (1.f - wy);
            const float w10 = wgt * wx * (1.f - wy);
            const float w01 = wgt * (1.f - wx) * wy;
            const float w11 = wgt * wx * wy;
            TAP(ya & xa, rbase, w00)
            TAP(ya & xb, rbase + 1, w10)
            TAP(yb & xa, rbase + Wl, w01)
            TAP(yb & xb, rbase + Wl + 1, w11)
        }
    }
#undef TAP
    a0 += __shfl_xor(a0, 32);
    a1 += __shfl_xor(a1, 32);
    a2 += __shfl_xor(a2, 32);
    a3 += __shfl_xor(a3, 32);
    if (pp == 0) {
        short4 o;
        o.x = f2bf(a0); o.y = f2bf(a1); o.z = f2bf(a2); o.w = f2bf(a3);
        *reinterpret_cast<short4*>(&out[((size_t)z * NTOK + bq) * 256 + co]) = o;
    }
}

extern "C" void kernel_launch(void* const* d_in, const int* in_sizes, int n_in,
                              void* d_out, int out_size, void* d_ws, size_t ws_size,
                              hipStream_t stream) {
    const float* tgt[2] = {(const float*)d_in[0], (const float*)d_in[1]};
    const float* pos[2] = {(const float*)d_in[2], (const float*)d_in[3]};
    const float* ref[2] = {(const float*)d_in[4], (const float*)d_in[5]};
    const float* src[2] = {(const float*)d_in[6], (const float*)d_in[7]};
    const float* sa_in_w  = (const float*)d_in[8];
    const float* sa_in_b  = (const float*)d_in[9];
    const float* sa_out_w = (const float*)d_in[10];
    const float* sa_out_b = (const float*)d_in[11];
    const float* ln_w = (const float*)d_in[12];
    const float* ln_b = (const float*)d_in[13];
    const float* ffn_w1 = (const float*)d_in[14];
    const float* ffn_b1 = (const float*)d_in[15];
    const float* ffn_w2 = (const float*)d_in[16];
    const float* ffn_b2 = (const float*)d_in[17];
    const float* val_w = (const float*)d_in[18];
    const float* val_b = (const float*)d_in[19];
    const float* off_w = (const float*)d_in[20];
    const float* off_b = (const float*)d_in[21];
    const float* aw_w = (const float*)d_in[22];
    const float* aw_b = (const float*)d_in[23];
    const float* cout_w = (const float*)d_in[24];
    const float* cout_b = (const float*)d_in[25];

    char* base = (char*)d_ws;
    size_t off = 0;
    auto alloc = [&](size_t bytes) -> char* {
        char* p = base + off;
        off += (bytes + 255) & ~(size_t)255;
        return p;
    };
    short* wbf   = (short*)alloc((size_t)2031616 * 2);
    float* baw   = (float*)alloc(768 * 4);
    short* qb_bf = (short*)alloc((size_t)2 * STOK * 2);
    short* tgtb  = (short*)alloc((size_t)2 * STOK * 2);
    float* qkv   = (float*)alloc((size_t)2 * 921600 * 4);
    short* attno = (short*)alloc((size_t)2 * STOK * 2);
    short* qc_bf = (short*)alloc((size_t)2 * STOK * 2);
    float* tgt2T = (float*)alloc((size_t)STOK * 4);
    float* oawb  = (float*)alloc((size_t)2 * NTOK * 384 * 4);
    short* valb  = (short*)alloc((size_t)2 * MVAL * 256 * 2);
    short* samp  = (short*)alloc((size_t)2 * STOK * 2);
    short* ln1b  = (short*)alloc((size_t)2 * STOK * 2);
    float* ln1f  = (float*)alloc((size_t)2 * STOK * 4);
    short* ffnh  = (short*)alloc((size_t)2 * NTOK * 1024 * 2);

    // weight sub-offsets (elements)
    short* sa_in_bf  = wbf + 0;        // 393216
    short* sa_out_bf = wbf + 393216;   // 131072
    short* ffn1_bf   = wbf + 524288;   // 524288
    short* ffn2_bf   = wbf + 1048576;  // 524288
    short* val_bf    = wbf + 1572864;  // 131072
    short* cout_bf   = wbf + 1703936;  // 131072
    short* oaw_bf    = wbf + 1835008;  // 196608 = 2 x (off 65536 + aw 32768)

    float* out0 = (float*)d_out;
    float* out1 = out0 + STOK;
    float* out2 = out1 + STOK;   // F_RGB = t2_RGB
    float* out3 = out2 + STOK;   // F_T

    const dim3 b256(256);

    // 1. weights -> bf16 (off/aw concatenated per z)
    WcvtArgs wa;
    wa.s[0] = sa_in_w;        wa.d[0] = sa_in_bf;       wa.n[0] = 393216;
    wa.s[1] = sa_out_w;       wa.d[1] = sa_out_bf;      wa.n[1] = 131072;
    wa.s[2] = ffn_w1;         wa.d[2] = ffn1_bf;        wa.n[2] = 524288;
    wa.s[3] = ffn_w2;         wa.d[3] = ffn2_bf;        wa.n[3] = 524288;
    wa.s[4] = val_w;          wa.d[4] = val_bf;         wa.n[4] = 131072;
    wa.s[5] = cout_w;         wa.d[5] = cout_bf;        wa.n[5] = 131072;
    wa.s[6] = off_w;          wa.d[6] = oaw_bf;         wa.n[6] = 65536;
    wa.s[7] = aw_w;           wa.d[7] = oaw_bf + 65536; wa.n[7] = 32768;
    wa.s[8] = off_w + 65536;  wa.d[8] = oaw_bf + 98304; wa.n[8] = 65536;
    wa.s[9] = aw_w + 32768;   wa.d[9] = oaw_bf + 163840;wa.n[9] = 32768;
    wcvt<<<dim3(128, 10), b256, 0, stream>>>(wa);

    // 2. activation prep + bias concat
    prep_act<<<dim3(150, 2), b256, 0, stream>>>(tgt[0], tgt[1], pos[0], pos[1],
                                                qb_bf, tgtb, off_b, aw_b, baw);

    // 3. value projections (BN=64, 24 KB LDS, 6 blocks/CU, XCD swizzle)
    gemm_val<<<dim3(8912), b256, 0, stream>>>(src[1], src[0], val_bf, val_b, valb);

    // 4. merged in-proj: x<4 -> qk from qb ; x>=4 -> v from tgtb (N=768 total)
    gemm_bf16<false, false, false, 64, 4><<<dim3(6, 19, 2), b256, 0, stream>>>(
        qb_bf, tgtb, 4, (size_t)STOK, 256, sa_in_bf, 196608, 256, sa_in_b, 768,
        nullptr, nullptr, 0, qkv, 921600, 768, NTOK);

    // 5. attention -> attno bf16
    attn2_kernel<<<dim3(10, 32, 2), b256, 0, stream>>>(qkv, attno);

    // 6. out-proj + residual(tgt) + norm2 fused -> qc_bf, tgt2T
    gemm_ln<4, 0><<<dim3(1, 19, 2), b256, 0, stream>>>(
        attno, (size_t)STOK, 256, sa_out_bf, 65536, sa_out_b, 256,
        tgt[0], tgt[1], ln_w, ln_b, pos[0], pos[1],
        qc_bf, tgt2T, nullptr, nullptr, NTOK);

    // 7. fused offsets+aw logits (N=384) -> oawb
    gemm_bf16<false, false, false, 64, 4><<<dim3(3, 19, 2), b256, 0, stream>>>(
        qc_bf, nullptr, 1 << 30, (size_t)STOK, 256, oaw_bf, 98304, 256, baw, 384,
        nullptr, nullptr, 0, oawb, (size_t)NTOK * 384, 384, NTOK);

    // 8. sampling (fused softmax) -> samp bf16
    sample_kernel<<<dim3(600, 2), b256, 0, stream>>>(valb, oawb, ref[0], ref[1], samp);

    // 9. cout -> out2/out3 (t2_RGB / t2_T)
    gemm_bf16<false, false, false, 64, 4><<<dim3(2, 19, 2), b256, 0, stream>>>(
        samp, nullptr, 1 << 30, (size_t)STOK, 256, cout_bf, 65536, 256, cout_b, 256,
        nullptr, nullptr, 0, out2, (size_t)STOK, 256, NTOK);

    // 10. norm1 (cross residuals fused)
    ln1_fused<<<dim3(NTOK, 2), b256, 0, stream>>>(tgt2T, out2, out3, ln_w, ln_b, ln1b, ln1f);

    // 11. FFN1 (ReLU, bf16 out)
    gemm_bf16<false, true, true, 64, 4><<<dim3(8, 19, 2), b256, 0, stream>>>(
        ln1b, nullptr, 1 << 30, (size_t)STOK, 256, ffn1_bf, 262144, 256, ffn_b1, 1024,
        nullptr, nullptr, 0, ffnh, (size_t)NTOK * 1024, 1024, NTOK);

    // 12. FFN2 + residual(ln1f) + norm3 fused -> out0/out1
    gemm_ln<16, 1><<<dim3(1, 19, 2), b256, 0, stream>>>(
        ffnh, (size_t)NTOK * 1024, 1024, ffn2_bf, 262144, ffn_b2, 256,
        ln1f, ln1f + STOK, ln_w, ln_b, nullptr, nullptr,
        nullptr, nullptr, out0, out1, NTOK);
}

// Round 15
// 189.400 us; speedup vs baseline: 1.1758x; 1.1758x over previous
//
#include <hip/hip_runtime.h>
#include <hip/hip_bf16.h>
#include <cstddef>
#include <math.h>

#define NTOK 1200          // B*NQ = 4*300
#define LTOT_C 17821
#define MVAL 71284         // B*LTOT
#define STOK (NTOK * 256)  // 307200

typedef __attribute__((ext_vector_type(8))) short bhalf8;
typedef __attribute__((ext_vector_type(4))) float f32x4;

static __device__ __forceinline__ short f2bf(float f) {
    unsigned u = __builtin_bit_cast(unsigned, f);
    u += 0x7fffu + ((u >> 16) & 1u);   // RNE
    return (short)(u >> 16);
}
static __device__ __forceinline__ float bf2f(short s) {
    unsigned u = ((unsigned)(unsigned short)s) << 16;
    return __builtin_bit_cast(float, u);
}
static __device__ __forceinline__ bhalf8 cvt8(float4 a, float4 b) {
    bhalf8 h;
    h[0] = f2bf(a.x); h[1] = f2bf(a.y); h[2] = f2bf(a.z); h[3] = f2bf(a.w);
    h[4] = f2bf(b.x); h[5] = f2bf(b.y); h[6] = f2bf(b.z); h[7] = f2bf(b.w);
    return h;
}
// async global -> LDS, 16B per lane; lds dest is wave-uniform base + lane*16
static __device__ __forceinline__ void gload_lds16(const void* g, void* l) {
    __builtin_amdgcn_global_load_lds(
        (const __attribute__((address_space(1))) void*)g,
        (__attribute__((address_space(3))) void*)l, 16, 0, 0);
}

// ---------------- weight convert fp32 -> bf16 (10 tasks) ----------------
struct WcvtArgs { const float* s[10]; short* d[10]; int n[10]; };
__global__ __launch_bounds__(256) void wcvt(WcvtArgs a) {
    const int ti = blockIdx.y;
    const float* s = a.s[ti];
    short* d = a.d[ti];
    const int n = a.n[ti];
    for (int base = (blockIdx.x * 256 + threadIdx.x) * 8; base < n; base += gridDim.x * 256 * 8) {
        const float4 f0 = *reinterpret_cast<const float4*>(s + base);
        const float4 f1 = *reinterpret_cast<const float4*>(s + base + 4);
        *reinterpret_cast<bhalf8*>(d + base) = cvt8(f0, f1);
    }
}

// ---------------- activation prep ----------------
__global__ __launch_bounds__(256) void prep_act(
    const float* __restrict__ tgt0, const float* __restrict__ tgt1,
    const float* __restrict__ pos0, const float* __restrict__ pos1,
    short* __restrict__ qb_bf, short* __restrict__ tgtb,
    const float* __restrict__ off_b, const float* __restrict__ aw_b,
    float* __restrict__ baw)
{
    const int z = blockIdx.y;
    if (blockIdx.x == 0 && z == 0) {
        for (int i = threadIdx.x; i < 768; i += 256) {
            const int zz = i / 384, j = i - zz * 384;
            baw[i] = (j < 256) ? off_b[zz * 256 + j] : aw_b[zz * 128 + (j - 256)];
        }
    }
    const float* tg = z ? tgt1 : tgt0;
    const float* ps = z ? pos1 : pos0;
    const int base = (blockIdx.x * 256 + threadIdx.x) * 8;
    if (base >= STOK) return;
    const float4 t0 = *reinterpret_cast<const float4*>(tg + base);
    const float4 t1 = *reinterpret_cast<const float4*>(tg + base + 4);
    const float4 p0 = *reinterpret_cast<const float4*>(ps + base);
    const float4 p1 = *reinterpret_cast<const float4*>(ps + base + 4);
    float4 s0 = make_float4(t0.x + p0.x, t0.y + p0.y, t0.z + p0.z, t0.w + p0.w);
    float4 s1 = make_float4(t1.x + p1.x, t1.y + p1.y, t1.z + p1.z, t1.w + p1.w);
    *reinterpret_cast<bhalf8*>(qb_bf + (size_t)z * STOK + base) = cvt8(s0, s1);
    *reinterpret_cast<bhalf8*>(tgtb + (size_t)z * STOK + base) = cvt8(t0, t1);
}

// ---------------- value projection: r12 hybrid pipeline + XCD swizzle (proven best) ------
// Tile 64(M) x 128(N), 4 waves (2x2), BK=64, NK=4.
// A fp32->reg (issued early) -> bf16 ds_write between two barriers (single 8 KB buffer);
// W async global_load_lds double-buffered (2 x 16 KB).  LDS 40 KB -> 4 blocks/CU.
// Grid: 1D 4456 = 8*557, bijective XCD chunking.
__global__ __launch_bounds__(256) void gemm_val(
    const float* __restrict__ A0, const float* __restrict__ A1,
    const short* __restrict__ Wbf, const float* __restrict__ bias,
    short* __restrict__ C)
{
    __shared__ alignas(16) short As[64 * 64];       // 8 KB (single buffer)
    __shared__ alignas(16) short Bs[2][128 * 64];   // 2 x 16 KB
    const int i = blockIdx.x;                       // 4456 = 8 * 557
    const int widx = (i & 7) * 557 + (i >> 3);      // bijective XCD chunking
    const int x = widx & 1;
    const int yz = widx >> 1;
    const int z = yz / 1114;
    const int y = yz - z * 1114;
    const float* A = z ? A1 : A0;
    const short* W = Wbf + (size_t)z * 65536;
    const float* bz = bias + z * 256;
    short* Cz = C + (size_t)z * MVAL * 256;
    const int t = threadIdx.x;
    const int wave = t >> 6, lane = t & 63;
    const int l15 = lane & 15, l4 = lane >> 4;
    const int wr = wave >> 1, wc = wave & 1;
    const int bm = y * 64, bn = x * 128;
    f32x4 acc[2][4] = {};

    const int nr8 = lane >> 3, q8 = lane & 7;
    auto stageW = [&](int k0, int buf) {
        #pragma unroll
        for (int ii = 0; ii < 4; ++ii) {
            const int c = wave * 4 + ii;
            const int n = c * 8 + nr8;
            gload_lds16(W + (size_t)(bn + n) * 256 + k0 + ((q8 ^ nr8) << 3),
                        (char*)&Bs[buf][0] + c * 1024);
        }
    };
    float4 paf[2][2];
    auto issueA = [&](int k0) {
        #pragma unroll
        for (int ii = 0; ii < 2; ++ii) {
            const int G = t + ii * 256;
            const int m = G >> 3, g = G & 7;
            const int row = min(bm + m, MVAL - 1);
            const float* s = A + (size_t)row * 256 + k0 + g * 8;
            paf[ii][0] = *reinterpret_cast<const float4*>(s);
            paf[ii][1] = *reinterpret_cast<const float4*>(s + 4);
        }
    };
    auto commitA = [&]() {
        #pragma unroll
        for (int ii = 0; ii < 2; ++ii) {
            const int G = t + ii * 256;
            const int m = G >> 3, g = G & 7;
            *reinterpret_cast<bhalf8*>(&As[m * 64 + ((g ^ (m & 7)) << 3)]) =
                cvt8(paf[ii][0], paf[ii][1]);
        }
    };
    auto compute = [&](int wbuf) {
        #pragma unroll
        for (int kf = 0; kf < 2; ++kf) {
            bhalf8 af[2], bfv[4];
            #pragma unroll
            for (int mf = 0; mf < 2; ++mf) {
                const int m = wr * 32 + (mf << 4) + l15;
                const int g = ((kf << 2) + l4) ^ (m & 7);
                af[mf] = *reinterpret_cast<const bhalf8*>(&As[m * 64 + (g << 3)]);
            }
            #pragma unroll
            for (int nf = 0; nf < 4; ++nf) {
                const int n = (wc << 6) + (nf << 4) + l15;
                const int g = ((kf << 2) + l4) ^ (n & 7);
                bfv[nf] = *reinterpret_cast<const bhalf8*>(&Bs[wbuf][n * 64 + (g << 3)]);
            }
            #pragma unroll
            for (int mf = 0; mf < 2; ++mf)
                #pragma unroll
                for (int nf = 0; nf < 4; ++nf)
                    acc[mf][nf] = __builtin_amdgcn_mfma_f32_16x16x32_bf16(
                        af[mf], bfv[nf], acc[mf][nf], 0, 0, 0);
        }
    };

    issueA(0);
    stageW(0, 0);
    commitA();
    __syncthreads();                    // A buf + W buf0 ready
    #pragma unroll
    for (int ks = 0; ks < 4; ++ks) {
        const int cur = ks & 1, nxt = cur ^ 1;
        if (ks + 1 < 4) {
            issueA((ks + 1) << 6);      // global->reg, flies under compute
            stageW((ks + 1) << 6, nxt); // async, flies under compute
        }
        compute(cur);
        if (ks + 1 < 4) {
            __syncthreads();            // all waves done reading As; W(nxt) drained
            commitA();
            __syncthreads();            // A buffer ready
        }
    }

    float br[4];
    #pragma unroll
    for (int nf = 0; nf < 4; ++nf) br[nf] = bz[bn + (wc << 6) + (nf << 4) + l15];
    #pragma unroll
    for (int mf = 0; mf < 2; ++mf) {
        #pragma unroll
        for (int j = 0; j < 4; ++j) {
            const int row = bm + wr * 32 + (mf << 4) + (l4 << 2) + j;
            if (row >= MVAL) continue;
            const int colbase = bn + (wc << 6);
            #pragma unroll
            for (int nf = 0; nf < 4; ++nf)
                Cz[(size_t)row * 256 + colbase + (nf << 4) + l15] = f2bf(acc[mf][nf][j] + br[nf]);
        }
    }
}

// ---------------- unified bf16 MFMA GEMM (bf16 A): async gload_lds, dbuf ----------------
// Optional blockIdx.x split: blocks with x >= xsplit read Av2 instead of Av.
template<bool HASRES, bool RELU, bool OUT_BF16, int BM, int NK>
__global__ __launch_bounds__(256) void gemm_bf16(
    const short* __restrict__ Av, const short* __restrict__ Av2, int xsplit,
    size_t aStrideZ, int lda,
    const short* __restrict__ Wv, size_t wStrideZ, int ldw,
    const float* __restrict__ bias, size_t biasStrideZ,
    const float* __restrict__ Res0, const float* __restrict__ Res1, int ldr,
    void* __restrict__ Cv, size_t cStrideZ, int ldc,
    int M)
{
    constexpr int MFR = BM / 32;
    constexpr int ACW = BM / 32;
    __shared__ alignas(16) short As[2][BM * 64];
    __shared__ alignas(16) short Bs[2][128 * 64];
    const int z = blockIdx.z;
    const short* Abase = (Av2 != nullptr && (int)blockIdx.x >= xsplit) ? Av2 : Av;
    const short* W = Wv + (size_t)z * wStrideZ;
    const float* bz = bias + (size_t)z * biasStrideZ;
    const int t = threadIdx.x;
    const int wave = t >> 6, lane = t & 63;
    const int l15 = lane & 15, l4 = lane >> 4;
    const int wr = wave >> 1, wc = wave & 1;
    const int bm = blockIdx.y * BM, bn = blockIdx.x * 128;
    f32x4 acc[MFR][4] = {};

    const int nr8 = lane >> 3, q8 = lane & 7;
    auto stageW = [&](int k0, int buf) {
        #pragma unroll
        for (int i = 0; i < 4; ++i) {
            const int c = wave * 4 + i;
            const int n = c * 8 + nr8;
            gload_lds16(W + (size_t)(bn + n) * ldw + k0 + ((q8 ^ nr8) << 3),
                        (char*)&Bs[buf][0] + c * 1024);
        }
    };
    auto stageA = [&](int k0, int buf) {
        #pragma unroll
        for (int i = 0; i < ACW; ++i) {
            const int c = wave * ACW + i;
            const int m = c * 8 + nr8;
            const int row = min(bm + m, M - 1);
            gload_lds16(Abase + (size_t)z * aStrideZ + (size_t)row * lda + k0 + ((q8 ^ (m & 7)) << 3),
                        (char*)&As[buf][0] + c * 1024);
        }
    };
    auto compute = [&](int buf) {
        #pragma unroll
        for (int kf = 0; kf < 2; ++kf) {
            bhalf8 af[MFR], bfv[4];
            #pragma unroll
            for (int mf = 0; mf < MFR; ++mf) {
                const int m = wr * (BM / 2) + (mf << 4) + l15;
                const int g = ((kf << 2) + l4) ^ (m & 7);
                af[mf] = *reinterpret_cast<const bhalf8*>(&As[buf][m * 64 + (g << 3)]);
            }
            #pragma unroll
            for (int nf = 0; nf < 4; ++nf) {
                const int n = (wc << 6) + (nf << 4) + l15;
                const int g = ((kf << 2) + l4) ^ (n & 7);
                bfv[nf] = *reinterpret_cast<const bhalf8*>(&Bs[buf][n * 64 + (g << 3)]);
            }
            #pragma unroll
            for (int mf = 0; mf < MFR; ++mf)
                #pragma unroll
                for (int nf = 0; nf < 4; ++nf)
                    acc[mf][nf] = __builtin_amdgcn_mfma_f32_16x16x32_bf16(
                        af[mf], bfv[nf], acc[mf][nf], 0, 0, 0);
        }
    };

    stageA(0, 0);
    stageW(0, 0);
    __syncthreads();
    #pragma unroll
    for (int ks = 0; ks < NK; ++ks) {
        const int cur = ks & 1, nxt = cur ^ 1;
        if (ks + 1 < NK) {
            stageA((ks + 1) << 6, nxt);
            stageW((ks + 1) << 6, nxt);
        }
        compute(cur);
        __syncthreads();
    }

    const float* Rz = HASRES ? (z ? Res1 : Res0) : nullptr;
    float br[4];
    #pragma unroll
    for (int nf = 0; nf < 4; ++nf) br[nf] = bz[bn + (wc << 6) + (nf << 4) + l15];
    #pragma unroll
    for (int mf = 0; mf < MFR; ++mf) {
        #pragma unroll
        for (int j = 0; j < 4; ++j) {
            const int row = bm + wr * (BM / 2) + (mf << 4) + (l4 << 2) + j;
            if (row >= M) continue;
            const int colbase = bn + (wc << 6);
            #pragma unroll
            for (int nf = 0; nf < 4; ++nf) {
                const int col = colbase + (nf << 4) + l15;
                float v = acc[mf][nf][j] + br[nf];
                if (HASRES) v += Rz[(size_t)row * ldr + col];
                if (RELU) v = fmaxf(v, 0.f);
                if (OUT_BF16)
                    ((short*)Cv + (size_t)z * cStrideZ)[(size_t)row * ldc + col] = f2bf(v);
                else
                    ((float*)Cv + (size_t)z * cStrideZ)[(size_t)row * ldc + col] = v;
            }
        }
    }
}

// ---------------- self-attention: key-parallel online softmax, bf16 out ----------------
__global__ __launch_bounds__(256) void attn2_kernel(
    const float* __restrict__ qkv_base, short* __restrict__ out_base)
{
    const float scale = 0.17677669529663687f;  // 1/sqrt(32)
    const float* qkv = qkv_base + (size_t)blockIdx.z * 921600;
    short* outp = out_base + (size_t)blockIdx.z * STOK;
    const int b = blockIdx.y >> 3, h = blockIdx.y & 7;
    const int t = threadIdx.x;
    const int ql = t & 31;
    const int kg = t >> 5;
    const int q = blockIdx.x * 32 + ql;
    const bool act = q < 300;
    const float* base = qkv + (size_t)b * 300 * 768;

    float qreg[32];
    if (act) {
        const float4* qp = reinterpret_cast<const float4*>(base + (size_t)q * 768 + h * 32);
        #pragma unroll
        for (int d4 = 0; d4 < 8; ++d4) {
            const float4 v = qp[d4];
            qreg[d4 * 4 + 0] = v.x; qreg[d4 * 4 + 1] = v.y;
            qreg[d4 * 4 + 2] = v.z; qreg[d4 * 4 + 3] = v.w;
        }
    }
    __shared__ float Ks[64][32];
    __shared__ float Vs[64][32];
    float m = -1e30f, l = 0.f, o[32];
    #pragma unroll
    for (int d = 0; d < 32; ++d) o[d] = 0.f;

    for (int k0 = 0; k0 < 300; k0 += 64) {
        const int cnt = min(64, 300 - k0);
        __syncthreads();
        for (int i = t; i < cnt * 32; i += 256) {
            const int kr = i >> 5, d = i & 31;
            Ks[kr][d] = base[(size_t)(k0 + kr) * 768 + 256 + h * 32 + d];
            Vs[kr][d] = base[(size_t)(k0 + kr) * 768 + 512 + h * 32 + d];
        }
        __syncthreads();
        if (act) {
            for (int kk = kg; kk < cnt; kk += 8) {
                const float4* krow = reinterpret_cast<const float4*>(&Ks[kk][0]);
                float s = 0.f;
                #pragma unroll
                for (int d4 = 0; d4 < 8; ++d4) {
                    const float4 kv = krow[d4];
                    s += qreg[d4 * 4 + 0] * kv.x + qreg[d4 * 4 + 1] * kv.y
                       + qreg[d4 * 4 + 2] * kv.z + qreg[d4 * 4 + 3] * kv.w;
                }
                s *= scale;
                const float4* vrow = reinterpret_cast<const float4*>(&Vs[kk][0]);
                if (s <= m) {
                    const float e = __expf(s - m);
                    l += e;
                    #pragma unroll
                    for (int d4 = 0; d4 < 8; ++d4) {
                        const float4 vv = vrow[d4];
                        o[d4 * 4 + 0] += e * vv.x; o[d4 * 4 + 1] += e * vv.y;
                        o[d4 * 4 + 2] += e * vv.z; o[d4 * 4 + 3] += e * vv.w;
                    }
                } else {
                    const float c = __expf(m - s);
                    l = l * c + 1.f;
                    #pragma unroll
                    for (int d4 = 0; d4 < 8; ++d4) {
                        const float4 vv = vrow[d4];
                        o[d4 * 4 + 0] = o[d4 * 4 + 0] * c + vv.x;
                        o[d4 * 4 + 1] = o[d4 * 4 + 1] * c + vv.y;
                        o[d4 * 4 + 2] = o[d4 * 4 + 2] * c + vv.z;
                        o[d4 * 4 + 3] = o[d4 * 4 + 3] * c + vv.w;
                    }
                    m = s;
                }
            }
        }
    }
    __shared__ float pm[32][8];
    __shared__ float pl[32][8];
    __shared__ float po[8][32][33];
    pm[ql][kg] = m; pl[ql][kg] = l;
    #pragma unroll
    for (int d = 0; d < 32; ++d) po[kg][d][ql] = o[d];
    __syncthreads();
    if (kg == 0) {
        float M = pm[ql][0];
        #pragma unroll
        for (int i = 1; i < 8; ++i) M = fmaxf(M, pm[ql][i]);
        float L = 0.f;
        #pragma unroll
        for (int i = 0; i < 8; ++i) L += pl[ql][i] * __expf(pm[ql][i] - M);
        const float invL = 1.f / L;
        #pragma unroll
        for (int i = 0; i < 8; ++i) pm[ql][i] = __expf(pm[ql][i] - M) * invL;
    }
    __syncthreads();
    if (act) {
        #pragma unroll
        for (int dd = 0; dd < 4; ++dd) {
            const int d = kg * 4 + dd;
            float v = 0.f;
            #pragma unroll
            for (int i = 0; i < 8; ++i) v += pm[ql][i] * po[i][d][ql];
            outp[((size_t)b * 300 + q) * 256 + h * 32 + d] = f2bf(v);
        }
    }
}

// ---------------- LN block-reduce body ----------------
#define LN_BODY(vexpr, widx)                                                  \
    const int row = blockIdx.x, t = threadIdx.x, z = blockIdx.y;              \
    (void)z;                                                                  \
    const int i = row * 256 + t;                                              \
    const float v = (vexpr);                                                  \
    __shared__ float r1[4], r2[4];                                            \
    float s = v;                                                              \
    _Pragma("unroll")                                                         \
    for (int o = 32; o; o >>= 1) s += __shfl_xor(s, o);                       \
    if ((t & 63) == 0) r1[t >> 6] = s;                                        \
    __syncthreads();                                                          \
    const float mean = (r1[0] + r1[1] + r1[2] + r1[3]) * (1.f / 256.f);       \
    const float dd = v - mean;                                                \
    float sq = dd * dd;                                                       \
    _Pragma("unroll")                                                         \
    for (int o = 32; o; o >>= 1) sq += __shfl_xor(sq, o);                     \
    if ((t & 63) == 0) r2[t >> 6] = sq;                                       \
    __syncthreads();                                                          \
    const float var = (r2[0] + r2[1] + r2[2] + r2[3]) * (1.f / 256.f);        \
    const float y = dd * rsqrtf(var + 1e-5f) * ln_w[(widx) * 256 + t]         \
                    + ln_b[(widx) * 256 + t];

__global__ __launch_bounds__(256) void ln2_fused(
    const float* __restrict__ presum, const float* __restrict__ pos0,
    const float* __restrict__ pos1, const float* __restrict__ ln_w,
    const float* __restrict__ ln_b, short* __restrict__ qc_bf,
    float* __restrict__ tgt2T)
{
    LN_BODY(presum[(size_t)z * STOK + i], z * 3 + 1)
    const float* pos = z ? pos1 : pos0;
    qc_bf[(size_t)z * STOK + i] = f2bf(y + pos[i]);
    if (z == 1) tgt2T[i] = y;
}

__global__ __launch_bounds__(256) void ln1_fused(
    const float* __restrict__ tgt2T, const float* __restrict__ out2,
    const float* __restrict__ out3, const float* __restrict__ ln_w,
    const float* __restrict__ ln_b, short* __restrict__ ln1b,
    float* __restrict__ ln1f)
{
    LN_BODY(tgt2T[row * 256 + t] + out2[row * 256 + t] + (z ? out3[row * 256 + t] : 0.f), z * 3 + 0)
    ln1b[(size_t)z * STOK + i] = f2bf(y);
    ln1f[(size_t)z * STOK + i] = y;
}

__global__ __launch_bounds__(256) void ln3_kernel(
    const float* __restrict__ ffny, const float* __restrict__ ln_w,
    const float* __restrict__ ln_b, float* __restrict__ o0,
    float* __restrict__ o1)
{
    LN_BODY(ffny[(size_t)z * STOK + i], z * 3 + 2)
    (z ? o1 : o0)[i] = y;
}

// ---------------- deformable sampling: short4 gathers, wave=(q, head-half) ----------------
__global__ __launch_bounds__(256) void sample_kernel(
    const short* __restrict__ valb, const float* __restrict__ oaw,
    const float* __restrict__ ref0, const float* __restrict__ ref1,
    short* __restrict__ out)
{
    const int HL[4] = {100, 50, 25, 13};
    const int WL[4] = {134, 67, 34, 17};
    const int ST[4] = {0, 13400, 16750, 17600};
    const int z = blockIdx.y;
    const int t = threadIdx.x;
    const int wave = t >> 6, lane = t & 63;
    const int qi = wave >> 1, hh = wave & 1;
    const int pp = lane >> 5, h4 = (lane >> 3) & 3, dl = lane & 7;
    const int h = hh * 4 + h4;
    const int bq = blockIdx.x * 2 + qi;
    const int b = bq / 300;
    const float* op = oaw + ((size_t)z * NTOK + bq) * 384;
    const float* offp = op + h * 32;
    const float* awp  = op + 256 + h * 16;
    const float* refp = (z ? ref1 : ref0) + (size_t)bq * 8;
    const short* vb = valb + (size_t)z * MVAL * 256 + (size_t)b * LTOT_C * 256;
    const int co = h * 32 + dl * 4;

    float w16[16];
    float mx = -1e30f;
    #pragma unroll
    for (int i = 0; i < 16; ++i) { w16[i] = awp[i]; mx = fmaxf(mx, w16[i]); }
    float ssum = 0.f;
    #pragma unroll
    for (int i = 0; i < 16; ++i) { w16[i] = __expf(w16[i] - mx); ssum += w16[i]; }
    const float sinv = 1.f / ssum;

    float a0 = 0.f, a1 = 0.f, a2 = 0.f, a3 = 0.f;
#define TAP(cond, ridx, wv)                                                   \
    if (cond) {                                                               \
        const short4 sv = *reinterpret_cast<const short4*>(                   \
            vb + (size_t)(ridx) * 256 + co);                                  \
        a0 += (wv) * bf2f(sv.x); a1 += (wv) * bf2f(sv.y);                     \
        a2 += (wv) * bf2f(sv.z); a3 += (wv) * bf2f(sv.w);                     \
    }
    #pragma unroll
    for (int l = 0; l < 4; ++l) {
        const int Wl = WL[l], Hl = HL[l];
        const float rx = refp[l * 2] * (float)Wl - 0.5f;
        const float ry = refp[l * 2 + 1] * (float)Hl - 0.5f;
        #pragma unroll
        for (int j = 0; j < 2; ++j) {
            const int p = pp * 2 + j;
            const float px = rx + offp[(l * 4 + p) * 2];
            const float py = ry + offp[(l * 4 + p) * 2 + 1];
            const float wgt = w16[l * 4 + p] * sinv;
            const float x0f = floorf(px), y0f = floorf(py);
            const float wx = px - x0f, wy = py - y0f;
            const int x0 = (int)x0f, y0 = (int)y0f;
            const bool xa = (x0 >= 0) & (x0 < Wl);
            const bool xb = (x0 >= -1) & (x0 < Wl - 1);
            const bool ya = (y0 >= 0) & (y0 < Hl);
            const bool yb = (y0 >= -1) & (y0 < Hl - 1);
            const int rbase = ST[l] + y0 * Wl + x0;
            const float w00 = wgt * (1.f - wx) * (1.f - wy);
            const float w10 = wgt * wx * (1.f - wy);
            const float w01 = wgt * (1.f - wx) * wy;
            const float w11 = wgt * wx * wy;
            TAP(ya & xa, rbase, w00)
            TAP(ya & xb, rbase + 1, w10)
            TAP(yb & xa, rbase + Wl, w01)
            TAP(yb & xb, rbase + Wl + 1, w11)
        }
    }
#undef TAP
    a0 += __shfl_xor(a0, 32);
    a1 += __shfl_xor(a1, 32);
    a2 += __shfl_xor(a2, 32);
    a3 += __shfl_xor(a3, 32);
    if (pp == 0) {
        short4 o;
        o.x = f2bf(a0); o.y = f2bf(a1); o.z = f2bf(a2); o.w = f2bf(a3);
        *reinterpret_cast<short4*>(&out[((size_t)z * NTOK + bq) * 256 + co]) = o;
    }
}

extern "C" void kernel_launch(void* const* d_in, const int* in_sizes, int n_in,
                              void* d_out, int out_size, void* d_ws, size_t ws_size,
                              hipStream_t stream) {
    const float* tgt[2] = {(const float*)d_in[0], (const float*)d_in[1]};
    const float* pos[2] = {(const float*)d_in[2], (const float*)d_in[3]};
    const float* ref[2] = {(const float*)d_in[4], (const float*)d_in[5]};
    const float* src[2] = {(const float*)d_in[6], (const float*)d_in[7]};
    const float* sa_in_w  = (const float*)d_in[8];
    const float* sa_in_b  = (const float*)d_in[9];
    const float* sa_out_w = (const float*)d_in[10];
    const float* sa_out_b = (const float*)d_in[11];
    const float* ln_w = (const float*)d_in[12];
    const float* ln_b = (const float*)d_in[13];
    const float* ffn_w1 = (const float*)d_in[14];
    const float* ffn_b1 = (const float*)d_in[15];
    const float* ffn_w2 = (const float*)d_in[16];
    const float* ffn_b2 = (const float*)d_in[17];
    const float* val_w = (const float*)d_in[18];
    const float* val_b = (const float*)d_in[19];
    const float* off_w = (const float*)d_in[20];
    const float* off_b = (const float*)d_in[21];
    const float* aw_w = (const float*)d_in[22];
    const float* aw_b = (const float*)d_in[23];
    const float* cout_w = (const float*)d_in[24];
    const float* cout_b = (const float*)d_in[25];

    char* base = (char*)d_ws;
    size_t off = 0;
    auto alloc = [&](size_t bytes) -> char* {
        char* p = base + off;
        off += (bytes + 255) & ~(size_t)255;
        return p;
    };
    short* wbf   = (short*)alloc((size_t)2031616 * 2);
    float* baw   = (float*)alloc(768 * 4);
    short* qb_bf = (short*)alloc((size_t)2 * STOK * 2);
    short* tgtb  = (short*)alloc((size_t)2 * STOK * 2);
    float* qkv   = (float*)alloc((size_t)2 * 921600 * 4);
    short* attno = (short*)alloc((size_t)2 * STOK * 2);
    float* presum= (float*)alloc((size_t)2 * STOK * 4);
    short* qc_bf = (short*)alloc((size_t)2 * STOK * 2);
    float* tgt2T = (float*)alloc((size_t)STOK * 4);
    float* oawb  = (float*)alloc((size_t)2 * NTOK * 384 * 4);
    short* valb  = (short*)alloc((size_t)2 * MVAL * 256 * 2);
    short* samp  = (short*)alloc((size_t)2 * STOK * 2);
    short* ln1b  = (short*)alloc((size_t)2 * STOK * 2);
    float* ln1f  = (float*)alloc((size_t)2 * STOK * 4);
    short* ffnh  = (short*)alloc((size_t)2 * NTOK * 1024 * 2);
    float* ffny  = (float*)alloc((size_t)2 * STOK * 4);

    // weight sub-offsets (elements)
    short* sa_in_bf  = wbf + 0;        // 393216
    short* sa_out_bf = wbf + 393216;   // 131072
    short* ffn1_bf   = wbf + 524288;   // 524288
    short* ffn2_bf   = wbf + 1048576;  // 524288
    short* val_bf    = wbf + 1572864;  // 131072
    short* cout_bf   = wbf + 1703936;  // 131072
    short* oaw_bf    = wbf + 1835008;  // 196608 = 2 x (off 65536 + aw 32768)

    float* out0 = (float*)d_out;
    float* out1 = out0 + STOK;
    float* out2 = out1 + STOK;   // F_RGB = t2_RGB
    float* out3 = out2 + STOK;   // F_T

    const dim3 b256(256);

    // 1. weights -> bf16 (off/aw concatenated per z)
    WcvtArgs wa;
    wa.s[0] = sa_in_w;        wa.d[0] = sa_in_bf;       wa.n[0] = 393216;
    wa.s[1] = sa_out_w;       wa.d[1] = sa_out_bf;      wa.n[1] = 131072;
    wa.s[2] = ffn_w1;         wa.d[2] = ffn1_bf;        wa.n[2] = 524288;
    wa.s[3] = ffn_w2;         wa.d[3] = ffn2_bf;        wa.n[3] = 524288;
    wa.s[4] = val_w;          wa.d[4] = val_bf;         wa.n[4] = 131072;
    wa.s[5] = cout_w;         wa.d[5] = cout_bf;        wa.n[5] = 131072;
    wa.s[6] = off_w;          wa.d[6] = oaw_bf;         wa.n[6] = 65536;
    wa.s[7] = aw_w;           wa.d[7] = oaw_bf + 65536; wa.n[7] = 32768;
    wa.s[8] = off_w + 65536;  wa.d[8] = oaw_bf + 98304; wa.n[8] = 65536;
    wa.s[9] = aw_w + 32768;   wa.d[9] = oaw_bf + 163840;wa.n[9] = 32768;
    wcvt<<<dim3(128, 10), b256, 0, stream>>>(wa);

    // 2. activation prep + bias concat
    prep_act<<<dim3(150, 2), b256, 0, stream>>>(tgt[0], tgt[1], pos[0], pos[1],
                                                qb_bf, tgtb, off_b, aw_b, baw);

    // 3. value projections (r12 pipeline + XCD swizzle): z=0 <- src_T, z=1 <- src_RGB
    gemm_val<<<dim3(4456), b256, 0, stream>>>(src[1], src[0], val_bf, val_b, valb);

    // 4. merged in-proj: x<4 -> qk from qb ; x>=4 -> v from tgtb (N=768 total)
    gemm_bf16<false, false, false, 64, 4><<<dim3(6, 19, 2), b256, 0, stream>>>(
        qb_bf, tgtb, 4, (size_t)STOK, 256, sa_in_bf, 196608, 256, sa_in_b, 768,
        nullptr, nullptr, 0, qkv, 921600, 768, NTOK);

    // 5. attention -> attno bf16
    attn2_kernel<<<dim3(10, 32, 2), b256, 0, stream>>>(qkv, attno);

    // 6. out-proj + residual(tgt) -> presum fp32
    gemm_bf16<true, false, false, 64, 4><<<dim3(2, 19, 2), b256, 0, stream>>>(
        attno, nullptr, 1 << 30, (size_t)STOK, 256, sa_out_bf, 65536, 256, sa_out_b, 256,
        tgt[0], tgt[1], 256, presum, (size_t)STOK, 256, NTOK);

    // 7. norm2 + qc=bf16(LN+pos) + tgt2T
    ln2_fused<<<dim3(NTOK, 2), b256, 0, stream>>>(presum, pos[0], pos[1], ln_w, ln_b, qc_bf, tgt2T);

    // 8. fused offsets+aw logits (N=384) -> oawb
    gemm_bf16<false, false, false, 64, 4><<<dim3(3, 19, 2), b256, 0, stream>>>(
        qc_bf, nullptr, 1 << 30, (size_t)STOK, 256, oaw_bf, 98304, 256, baw, 384,
        nullptr, nullptr, 0, oawb, (size_t)NTOK * 384, 384, NTOK);

    // 9. sampling (fused softmax) -> samp bf16
    sample_kernel<<<dim3(600, 2), b256, 0, stream>>>(valb, oawb, ref[0], ref[1], samp);

    // 10. cout -> out2/out3 (t2_RGB / t2_T)
    gemm_bf16<false, false, false, 64, 4><<<dim3(2, 19, 2), b256, 0, stream>>>(
        samp, nullptr, 1 << 30, (size_t)STOK, 256, cout_bf, 65536, 256, cout_b, 256,
        nullptr, nullptr, 0, out2, (size_t)STOK, 256, NTOK);

    // 11. norm1 (cross residuals fused)
    ln1_fused<<<dim3(NTOK, 2), b256, 0, stream>>>(tgt2T, out2, out3, ln_w, ln_b, ln1b, ln1f);

    // 12. FFN1 (ReLU, bf16 out)
    gemm_bf16<false, true, true, 64, 4><<<dim3(8, 19, 2), b256, 0, stream>>>(
        ln1b, nullptr, 1 << 30, (size_t)STOK, 256, ffn1_bf, 262144, 256, ffn_b1, 1024,
        nullptr, nullptr, 0, ffnh, (size_t)NTOK * 1024, 1024, NTOK);

    // 13. FFN2 + residual(ln1f) -> ffny fp32
    gemm_bf16<true, false, false, 64, 16><<<dim3(2, 19, 2), b256, 0, stream>>>(
        ffnh, nullptr, 1 << 30, (size_t)NTOK * 1024, 1024, ffn2_bf, 262144, 1024, ffn_b2, 256,
        ln1f, ln1f + STOK, 256, ffny, (size_t)STOK, 256, NTOK);

    // 14. norm3 -> out0/out1
    ln3_kernel<<<dim3(NTOK, 2), b256, 0, stream>>>(ffny, ln_w, ln_b, out0, out1);
}

// Round 16
// 188.823 us; speedup vs baseline: 1.1794x; 1.0031x over previous
//
#include <hip/hip_runtime.h>
#include <hip/hip_bf16.h>
#include <cstddef>
#include <math.h>

#define NTOK 1200          // B*NQ = 4*300
#define LTOT_C 17821
#define MVAL 71284         // B*LTOT
#define STOK (NTOK * 256)  // 307200

typedef __attribute__((ext_vector_type(8))) short bhalf8;
typedef __attribute__((ext_vector_type(4))) float f32x4;

static __device__ __forceinline__ short f2bf(float f) {
    unsigned u = __builtin_bit_cast(unsigned, f);
    u += 0x7fffu + ((u >> 16) & 1u);   // RNE
    return (short)(u >> 16);
}
static __device__ __forceinline__ float bf2f(short s) {
    unsigned u = ((unsigned)(unsigned short)s) << 16;
    return __builtin_bit_cast(float, u);
}
static __device__ __forceinline__ bhalf8 cvt8(float4 a, float4 b) {
    bhalf8 h;
    h[0] = f2bf(a.x); h[1] = f2bf(a.y); h[2] = f2bf(a.z); h[3] = f2bf(a.w);
    h[4] = f2bf(b.x); h[5] = f2bf(b.y); h[6] = f2bf(b.z); h[7] = f2bf(b.w);
    return h;
}
// async global -> LDS, 16B per lane; lds dest is wave-uniform base + lane*16
static __device__ __forceinline__ void gload_lds16(const void* g, void* l) {
    __builtin_amdgcn_global_load_lds(
        (const __attribute__((address_space(1))) void*)g,
        (__attribute__((address_space(3))) void*)l, 16, 0, 0);
}

// ---------------- combined weight-convert (tasks 0-9) + activation prep (tasks 10-11) ----
struct PrepArgs {
    const float* s[10]; short* d[10]; int n[10];
    const float* tgt0; const float* tgt1; const float* pos0; const float* pos1;
    short* qb_bf; short* tgtb;
    const float* off_b; const float* aw_b; float* baw;
};
__global__ __launch_bounds__(256) void prep_all(PrepArgs a) {
    const int task = blockIdx.y;
    if (task < 10) {
        const float* s = a.s[task];
        short* d = a.d[task];
        const int n = a.n[task];
        for (int base = (blockIdx.x * 256 + threadIdx.x) * 8; base < n;
             base += gridDim.x * 256 * 8) {
            const float4 f0 = *reinterpret_cast<const float4*>(s + base);
            const float4 f1 = *reinterpret_cast<const float4*>(s + base + 4);
            *reinterpret_cast<bhalf8*>(d + base) = cvt8(f0, f1);
        }
        return;
    }
    const int z = task - 10;
    if (blockIdx.x == 0 && z == 0) {
        for (int i = threadIdx.x; i < 768; i += 256) {
            const int zz = i / 384, j = i - zz * 384;
            a.baw[i] = (j < 256) ? a.off_b[zz * 256 + j] : a.aw_b[zz * 128 + (j - 256)];
        }
    }
    const float* tg = z ? a.tgt1 : a.tgt0;
    const float* ps = z ? a.pos1 : a.pos0;
    const int base = (blockIdx.x * 256 + threadIdx.x) * 8;
    if (base >= STOK) return;
    const float4 t0 = *reinterpret_cast<const float4*>(tg + base);
    const float4 t1 = *reinterpret_cast<const float4*>(tg + base + 4);
    const float4 p0 = *reinterpret_cast<const float4*>(ps + base);
    const float4 p1 = *reinterpret_cast<const float4*>(ps + base + 4);
    float4 s0 = make_float4(t0.x + p0.x, t0.y + p0.y, t0.z + p0.z, t0.w + p0.w);
    float4 s1 = make_float4(t1.x + p1.x, t1.y + p1.y, t1.z + p1.z, t1.w + p1.w);
    *reinterpret_cast<bhalf8*>(a.qb_bf + (size_t)z * STOK + base) = cvt8(s0, s1);
    *reinterpret_cast<bhalf8*>(a.tgtb + (size_t)z * STOK + base) = cvt8(t0, t1);
}

// ---------------- merged kernel: in-proj blocks (0..227) + value projection (228..4683) ---
// in-proj: BM=64 x BN=128 tile of qkv (N=768; x<4 -> A=qb (q,k), x>=4 -> A=tgtb (v)).
// val: r12-proven hybrid pipeline (A fp32->reg->bf16 ds_write single-buf; W gload_lds dbuf)
//      + bijective XCD chunking.  Shared LDS 48 KB -> 3 blocks/CU.
__global__ __launch_bounds__(256) void val_inproj(
    const float* __restrict__ A0, const float* __restrict__ A1,
    const short* __restrict__ val_bf, const float* __restrict__ val_b,
    short* __restrict__ valb,
    const short* __restrict__ qb_bf, const short* __restrict__ tgtb,
    const short* __restrict__ sa_in_bf, const float* __restrict__ sa_in_b,
    float* __restrict__ qkv)
{
    __shared__ alignas(16) short AsBuf[2][64 * 64];   // 16 KB
    __shared__ alignas(16) short Bs[2][128 * 64];     // 32 KB
    const int t = threadIdx.x;
    const int wave = t >> 6, lane = t & 63;
    const int l15 = lane & 15, l4 = lane >> 4;
    const int wr = wave >> 1, wc = wave & 1;
    const int nr8 = lane >> 3, q8 = lane & 7;
    const int bi = blockIdx.x;

    if (bi >= 228) {
        // ---------------- value projection ----------------
        const int i = bi - 228;                     // 0..4455 = 8*557
        const int widx = (i & 7) * 557 + (i >> 3);  // bijective XCD chunking
        const int x = widx & 1;
        const int yz = widx >> 1;
        const int z = yz / 1114;
        const int y = yz - z * 1114;
        const float* A = z ? A1 : A0;
        const short* W = val_bf + (size_t)z * 65536;
        const float* bz = val_b + z * 256;
        short* Cz = valb + (size_t)z * MVAL * 256;
        const int bm = y * 64, bn = x * 128;
        short* As = &AsBuf[0][0];                   // single 8 KB A buffer
        f32x4 acc[2][4] = {};

        auto stageW = [&](int k0, int buf) {
            #pragma unroll
            for (int ii = 0; ii < 4; ++ii) {
                const int c = wave * 4 + ii;
                const int n = c * 8 + nr8;
                gload_lds16(W + (size_t)(bn + n) * 256 + k0 + ((q8 ^ nr8) << 3),
                            (char*)&Bs[buf][0] + c * 1024);
            }
        };
        float4 paf[2][2];
        auto issueA = [&](int k0) {
            #pragma unroll
            for (int ii = 0; ii < 2; ++ii) {
                const int G = t + ii * 256;
                const int m = G >> 3, g = G & 7;
                const int row = min(bm + m, MVAL - 1);
                const float* s = A + (size_t)row * 256 + k0 + g * 8;
                paf[ii][0] = *reinterpret_cast<const float4*>(s);
                paf[ii][1] = *reinterpret_cast<const float4*>(s + 4);
            }
        };
        auto commitA = [&]() {
            #pragma unroll
            for (int ii = 0; ii < 2; ++ii) {
                const int G = t + ii * 256;
                const int m = G >> 3, g = G & 7;
                *reinterpret_cast<bhalf8*>(&As[m * 64 + ((g ^ (m & 7)) << 3)]) =
                    cvt8(paf[ii][0], paf[ii][1]);
            }
        };
        auto compute = [&](int wbuf) {
            #pragma unroll
            for (int kf = 0; kf < 2; ++kf) {
                bhalf8 af[2], bfv[4];
                #pragma unroll
                for (int mf = 0; mf < 2; ++mf) {
                    const int m = wr * 32 + (mf << 4) + l15;
                    const int g = ((kf << 2) + l4) ^ (m & 7);
                    af[mf] = *reinterpret_cast<const bhalf8*>(&As[m * 64 + (g << 3)]);
                }
                #pragma unroll
                for (int nf = 0; nf < 4; ++nf) {
                    const int n = (wc << 6) + (nf << 4) + l15;
                    const int g = ((kf << 2) + l4) ^ (n & 7);
                    bfv[nf] = *reinterpret_cast<const bhalf8*>(&Bs[wbuf][n * 64 + (g << 3)]);
                }
                #pragma unroll
                for (int mf = 0; mf < 2; ++mf)
                    #pragma unroll
                    for (int nf = 0; nf < 4; ++nf)
                        acc[mf][nf] = __builtin_amdgcn_mfma_f32_16x16x32_bf16(
                            af[mf], bfv[nf], acc[mf][nf], 0, 0, 0);
            }
        };

        issueA(0);
        stageW(0, 0);
        commitA();
        __syncthreads();
        #pragma unroll
        for (int ks = 0; ks < 4; ++ks) {
            const int cur = ks & 1, nxt = cur ^ 1;
            if (ks + 1 < 4) {
                issueA((ks + 1) << 6);
                stageW((ks + 1) << 6, nxt);
            }
            compute(cur);
            if (ks + 1 < 4) {
                __syncthreads();
                commitA();
                __syncthreads();
            }
        }

        float br[4];
        #pragma unroll
        for (int nf = 0; nf < 4; ++nf) br[nf] = bz[bn + (wc << 6) + (nf << 4) + l15];
        #pragma unroll
        for (int mf = 0; mf < 2; ++mf) {
            #pragma unroll
            for (int j = 0; j < 4; ++j) {
                const int row = bm + wr * 32 + (mf << 4) + (l4 << 2) + j;
                if (row >= MVAL) continue;
                const int colbase = bn + (wc << 6);
                #pragma unroll
                for (int nf = 0; nf < 4; ++nf)
                    Cz[(size_t)row * 256 + colbase + (nf << 4) + l15] =
                        f2bf(acc[mf][nf][j] + br[nf]);
            }
        }
    } else {
        // ---------------- merged in-proj (BM=64, NK=4, N=768) ----------------
        const int z = bi / 114;
        const int r = bi - z * 114;
        const int x = r / 19;           // 0..5
        const int y = r - x * 19;       // 0..18
        const short* Abase = (x < 4) ? qb_bf : tgtb;
        const short* W = sa_in_bf + (size_t)z * 196608;
        const float* bz = sa_in_b + z * 768;
        const int bm = y * 64, bn = x * 128;
        f32x4 acc[2][4] = {};

        auto stageW = [&](int k0, int buf) {
            #pragma unroll
            for (int ii = 0; ii < 4; ++ii) {
                const int c = wave * 4 + ii;
                const int n = c * 8 + nr8;
                gload_lds16(W + (size_t)(bn + n) * 256 + k0 + ((q8 ^ nr8) << 3),
                            (char*)&Bs[buf][0] + c * 1024);
            }
        };
        auto stageA = [&](int k0, int buf) {
            #pragma unroll
            for (int ii = 0; ii < 2; ++ii) {
                const int c = wave * 2 + ii;
                const int m = c * 8 + nr8;
                const int row = min(bm + m, NTOK - 1);
                gload_lds16(Abase + (size_t)z * STOK + (size_t)row * 256 + k0 + ((q8 ^ (m & 7)) << 3),
                            (char*)&AsBuf[buf][0] + c * 1024);
            }
        };
        auto compute = [&](int buf) {
            #pragma unroll
            for (int kf = 0; kf < 2; ++kf) {
                bhalf8 af[2], bfv[4];
                #pragma unroll
                for (int mf = 0; mf < 2; ++mf) {
                    const int m = wr * 32 + (mf << 4) + l15;
                    const int g = ((kf << 2) + l4) ^ (m & 7);
                    af[mf] = *reinterpret_cast<const bhalf8*>(&AsBuf[buf][m * 64 + (g << 3)]);
                }
                #pragma unroll
                for (int nf = 0; nf < 4; ++nf) {
                    const int n = (wc << 6) + (nf << 4) + l15;
                    const int g = ((kf << 2) + l4) ^ (n & 7);
                    bfv[nf] = *reinterpret_cast<const bhalf8*>(&Bs[buf][n * 64 + (g << 3)]);
                }
                #pragma unroll
                for (int mf = 0; mf < 2; ++mf)
                    #pragma unroll
                    for (int nf = 0; nf < 4; ++nf)
                        acc[mf][nf] = __builtin_amdgcn_mfma_f32_16x16x32_bf16(
                            af[mf], bfv[nf], acc[mf][nf], 0, 0, 0);
            }
        };

        stageA(0, 0);
        stageW(0, 0);
        __syncthreads();
        #pragma unroll
        for (int ks = 0; ks < 4; ++ks) {
            const int cur = ks & 1, nxt = cur ^ 1;
            if (ks + 1 < 4) {
                stageA((ks + 1) << 6, nxt);
                stageW((ks + 1) << 6, nxt);
            }
            compute(cur);
            __syncthreads();
        }

        float* Cz = qkv + (size_t)z * 921600;
        float br[4];
        #pragma unroll
        for (int nf = 0; nf < 4; ++nf) br[nf] = bz[bn + (wc << 6) + (nf << 4) + l15];
        #pragma unroll
        for (int mf = 0; mf < 2; ++mf) {
            #pragma unroll
            for (int j = 0; j < 4; ++j) {
                const int row = bm + wr * 32 + (mf << 4) + (l4 << 2) + j;
                if (row >= NTOK) continue;
                const int colbase = bn + (wc << 6);
                #pragma unroll
                for (int nf = 0; nf < 4; ++nf)
                    Cz[(size_t)row * 768 + colbase + (nf << 4) + l15] = acc[mf][nf][j] + br[nf];
            }
        }
    }
}

// ---------------- unified bf16 MFMA GEMM (bf16 A): async gload_lds, dbuf ----------------
template<bool HASRES, bool RELU, bool OUT_BF16, int BM, int NK>
__global__ __launch_bounds__(256) void gemm_bf16(
    const short* __restrict__ Av, size_t aStrideZ, int lda,
    const short* __restrict__ Wv, size_t wStrideZ, int ldw,
    const float* __restrict__ bias, size_t biasStrideZ,
    const float* __restrict__ Res0, const float* __restrict__ Res1, int ldr,
    void* __restrict__ Cv, size_t cStrideZ, int ldc,
    int M)
{
    constexpr int MFR = BM / 32;
    constexpr int ACW = BM / 32;
    __shared__ alignas(16) short As[2][BM * 64];
    __shared__ alignas(16) short Bs[2][128 * 64];
    const int z = blockIdx.z;
    const short* W = Wv + (size_t)z * wStrideZ;
    const float* bz = bias + (size_t)z * biasStrideZ;
    const int t = threadIdx.x;
    const int wave = t >> 6, lane = t & 63;
    const int l15 = lane & 15, l4 = lane >> 4;
    const int wr = wave >> 1, wc = wave & 1;
    const int bm = blockIdx.y * BM, bn = blockIdx.x * 128;
    f32x4 acc[MFR][4] = {};

    const int nr8 = lane >> 3, q8 = lane & 7;
    auto stageW = [&](int k0, int buf) {
        #pragma unroll
        for (int i = 0; i < 4; ++i) {
            const int c = wave * 4 + i;
            const int n = c * 8 + nr8;
            gload_lds16(W + (size_t)(bn + n) * ldw + k0 + ((q8 ^ nr8) << 3),
                        (char*)&Bs[buf][0] + c * 1024);
        }
    };
    auto stageA = [&](int k0, int buf) {
        #pragma unroll
        for (int i = 0; i < ACW; ++i) {
            const int c = wave * ACW + i;
            const int m = c * 8 + nr8;
            const int row = min(bm + m, M - 1);
            gload_lds16(Av + (size_t)z * aStrideZ + (size_t)row * lda + k0 + ((q8 ^ (m & 7)) << 3),
                        (char*)&As[buf][0] + c * 1024);
        }
    };
    auto compute = [&](int buf) {
        #pragma unroll
        for (int kf = 0; kf < 2; ++kf) {
            bhalf8 af[MFR], bfv[4];
            #pragma unroll
            for (int mf = 0; mf < MFR; ++mf) {
                const int m = wr * (BM / 2) + (mf << 4) + l15;
                const int g = ((kf << 2) + l4) ^ (m & 7);
                af[mf] = *reinterpret_cast<const bhalf8*>(&As[buf][m * 64 + (g << 3)]);
            }
            #pragma unroll
            for (int nf = 0; nf < 4; ++nf) {
                const int n = (wc << 6) + (nf << 4) + l15;
                const int g = ((kf << 2) + l4) ^ (n & 7);
                bfv[nf] = *reinterpret_cast<const bhalf8*>(&Bs[buf][n * 64 + (g << 3)]);
            }
            #pragma unroll
            for (int mf = 0; mf < MFR; ++mf)
                #pragma unroll
                for (int nf = 0; nf < 4; ++nf)
                    acc[mf][nf] = __builtin_amdgcn_mfma_f32_16x16x32_bf16(
                        af[mf], bfv[nf], acc[mf][nf], 0, 0, 0);
        }
    };

    stageA(0, 0);
    stageW(0, 0);
    __syncthreads();
    #pragma unroll
    for (int ks = 0; ks < NK; ++ks) {
        const int cur = ks & 1, nxt = cur ^ 1;
        if (ks + 1 < NK) {
            stageA((ks + 1) << 6, nxt);
            stageW((ks + 1) << 6, nxt);
        }
        compute(cur);
        __syncthreads();
    }

    const float* Rz = HASRES ? (z ? Res1 : Res0) : nullptr;
    float br[4];
    #pragma unroll
    for (int nf = 0; nf < 4; ++nf) br[nf] = bz[bn + (wc << 6) + (nf << 4) + l15];
    #pragma unroll
    for (int mf = 0; mf < MFR; ++mf) {
        #pragma unroll
        for (int j = 0; j < 4; ++j) {
            const int row = bm + wr * (BM / 2) + (mf << 4) + (l4 << 2) + j;
            if (row >= M) continue;
            const int colbase = bn + (wc << 6);
            #pragma unroll
            for (int nf = 0; nf < 4; ++nf) {
                const int col = colbase + (nf << 4) + l15;
                float v = acc[mf][nf][j] + br[nf];
                if (HASRES) v += Rz[(size_t)row * ldr + col];
                if (RELU) v = fmaxf(v, 0.f);
                if (OUT_BF16)
                    ((short*)Cv + (size_t)z * cStrideZ)[(size_t)row * ldc + col] = f2bf(v);
                else
                    ((float*)Cv + (size_t)z * cStrideZ)[(size_t)row * ldc + col] = v;
            }
        }
    }
}

// ---------------- self-attention: key-parallel online softmax, bf16 out ----------------
__global__ __launch_bounds__(256) void attn2_kernel(
    const float* __restrict__ qkv_base, short* __restrict__ out_base)
{
    const float scale = 0.17677669529663687f;  // 1/sqrt(32)
    const float* qkv = qkv_base + (size_t)blockIdx.z * 921600;
    short* outp = out_base + (size_t)blockIdx.z * STOK;
    const int b = blockIdx.y >> 3, h = blockIdx.y & 7;
    const int t = threadIdx.x;
    const int ql = t & 31;
    const int kg = t >> 5;
    const int q = blockIdx.x * 32 + ql;
    const bool act = q < 300;
    const float* base = qkv + (size_t)b * 300 * 768;

    float qreg[32];
    if (act) {
        const float4* qp = reinterpret_cast<const float4*>(base + (size_t)q * 768 + h * 32);
        #pragma unroll
        for (int d4 = 0; d4 < 8; ++d4) {
            const float4 v = qp[d4];
            qreg[d4 * 4 + 0] = v.x; qreg[d4 * 4 + 1] = v.y;
            qreg[d4 * 4 + 2] = v.z; qreg[d4 * 4 + 3] = v.w;
        }
    }
    __shared__ float Ks[64][32];
    __shared__ float Vs[64][32];
    float m = -1e30f, l = 0.f, o[32];
    #pragma unroll
    for (int d = 0; d < 32; ++d) o[d] = 0.f;

    for (int k0 = 0; k0 < 300; k0 += 64) {
        const int cnt = min(64, 300 - k0);
        __syncthreads();
        for (int i = t; i < cnt * 32; i += 256) {
            const int kr = i >> 5, d = i & 31;
            Ks[kr][d] = base[(size_t)(k0 + kr) * 768 + 256 + h * 32 + d];
            Vs[kr][d] = base[(size_t)(k0 + kr) * 768 + 512 + h * 32 + d];
        }
        __syncthreads();
        if (act) {
            for (int kk = kg; kk < cnt; kk += 8) {
                const float4* krow = reinterpret_cast<const float4*>(&Ks[kk][0]);
                float s = 0.f;
                #pragma unroll
                for (int d4 = 0; d4 < 8; ++d4) {
                    const float4 kv = krow[d4];
                    s += qreg[d4 * 4 + 0] * kv.x + qreg[d4 * 4 + 1] * kv.y
                       + qreg[d4 * 4 + 2] * kv.z + qreg[d4 * 4 + 3] * kv.w;
                }
                s *= scale;
                const float4* vrow = reinterpret_cast<const float4*>(&Vs[kk][0]);
                if (s <= m) {
                    const float e = __expf(s - m);
                    l += e;
                    #pragma unroll
                    for (int d4 = 0; d4 < 8; ++d4) {
                        const float4 vv = vrow[d4];
                        o[d4 * 4 + 0] += e * vv.x; o[d4 * 4 + 1] += e * vv.y;
                        o[d4 * 4 + 2] += e * vv.z; o[d4 * 4 + 3] += e * vv.w;
                    }
                } else {
                    const float c = __expf(m - s);
                    l = l * c + 1.f;
                    #pragma unroll
                    for (int d4 = 0; d4 < 8; ++d4) {
                        const float4 vv = vrow[d4];
                        o[d4 * 4 + 0] = o[d4 * 4 + 0] * c + vv.x;
                        o[d4 * 4 + 1] = o[d4 * 4 + 1] * c + vv.y;
                        o[d4 * 4 + 2] = o[d4 * 4 + 2] * c + vv.z;
                        o[d4 * 4 + 3] = o[d4 * 4 + 3] * c + vv.w;
                    }
                    m = s;
                }
            }
        }
    }
    __shared__ float pm[32][8];
    __shared__ float pl[32][8];
    __shared__ float po[8][32][33];
    pm[ql][kg] = m; pl[ql][kg] = l;
    #pragma unroll
    for (int d = 0; d < 32; ++d) po[kg][d][ql] = o[d];
    __syncthreads();
    if (kg == 0) {
        float M = pm[ql][0];
        #pragma unroll
        for (int i = 1; i < 8; ++i) M = fmaxf(M, pm[ql][i]);
        float L = 0.f;
        #pragma unroll
        for (int i = 0; i < 8; ++i) L += pl[ql][i] * __expf(pm[ql][i] - M);
        const float invL = 1.f / L;
        #pragma unroll
        for (int i = 0; i < 8; ++i) pm[ql][i] = __expf(pm[ql][i] - M) * invL;
    }
    __syncthreads();
    if (act) {
        #pragma unroll
        for (int dd = 0; dd < 4; ++dd) {
            const int d = kg * 4 + dd;
            float v = 0.f;
            #pragma unroll
            for (int i = 0; i < 8; ++i) v += pm[ql][i] * po[i][d][ql];
            outp[((size_t)b * 300 + q) * 256 + h * 32 + d] = f2bf(v);
        }
    }
}

// ---------------- LN block-reduce body ----------------
#define LN_BODY(vexpr, widx)                                                  \
    const int row = blockIdx.x, t = threadIdx.x, z = blockIdx.y;              \
    (void)z;                                                                  \
    const int i = row * 256 + t;                                              \
    const float v = (vexpr);                                                  \
    __shared__ float r1[4], r2[4];                                            \
    float s = v;                                                              \
    _Pragma("unroll")                                                         \
    for (int o = 32; o; o >>= 1) s += __shfl_xor(s, o);                       \
    if ((t & 63) == 0) r1[t >> 6] = s;                                        \
    __syncthreads();                                                          \
    const float mean = (r1[0] + r1[1] + r1[2] + r1[3]) * (1.f / 256.f);       \
    const float dd = v - mean;                                                \
    float sq = dd * dd;                                                       \
    _Pragma("unroll")                                                         \
    for (int o = 32; o; o >>= 1) sq += __shfl_xor(sq, o);                     \
    if ((t & 63) == 0) r2[t >> 6] = sq;                                       \
    __syncthreads();                                                          \
    const float var = (r2[0] + r2[1] + r2[2] + r2[3]) * (1.f / 256.f);        \
    const float y = dd * rsqrtf(var + 1e-5f) * ln_w[(widx) * 256 + t]         \
                    + ln_b[(widx) * 256 + t];

__global__ __launch_bounds__(256) void ln2_fused(
    const float* __restrict__ presum, const float* __restrict__ pos0,
    const float* __restrict__ pos1, const float* __restrict__ ln_w,
    const float* __restrict__ ln_b, short* __restrict__ qc_bf,
    float* __restrict__ tgt2T)
{
    LN_BODY(presum[(size_t)z * STOK + i], z * 3 + 1)
    const float* pos = z ? pos1 : pos0;
    qc_bf[(size_t)z * STOK + i] = f2bf(y + pos[i]);
    if (z == 1) tgt2T[i] = y;
}

__global__ __launch_bounds__(256) void ln1_fused(
    const float* __restrict__ tgt2T, const float* __restrict__ out2,
    const float* __restrict__ out3, const float* __restrict__ ln_w,
    const float* __restrict__ ln_b, short* __restrict__ ln1b,
    float* __restrict__ ln1f)
{
    LN_BODY(tgt2T[row * 256 + t] + out2[row * 256 + t] + (z ? out3[row * 256 + t] : 0.f), z * 3 + 0)
    ln1b[(size_t)z * STOK + i] = f2bf(y);
    ln1f[(size_t)z * STOK + i] = y;
}

__global__ __launch_bounds__(256) void ln3_kernel(
    const float* __restrict__ ffny, const float* __restrict__ ln_w,
    const float* __restrict__ ln_b, float* __restrict__ o0,
    float* __restrict__ o1)
{
    LN_BODY(ffny[(size_t)z * STOK + i], z * 3 + 2)
    (z ? o1 : o0)[i] = y;
}

// ---------------- deformable sampling: short4 gathers, wave=(q, head-half) ----------------
__global__ __launch_bounds__(256) void sample_kernel(
    const short* __restrict__ valb, const float* __restrict__ oaw,
    const float* __restrict__ ref0, const float* __restrict__ ref1,
    short* __restrict__ out)
{
    const int HL[4] = {100, 50, 25, 13};
    const int WL[4] = {134, 67, 34, 17};
    const int ST[4] = {0, 13400, 16750, 17600};
    const int z = blockIdx.y;
    const int t = threadIdx.x;
    const int wave = t >> 6, lane = t & 63;
    const int qi = wave >> 1, hh = wave & 1;
    const int pp = lane >> 5, h4 = (lane >> 3) & 3, dl = lane & 7;
    const int h = hh * 4 + h4;
    const int bq = blockIdx.x * 2 + qi;
    const int b = bq / 300;
    const float* op = oaw + ((size_t)z * NTOK + bq) * 384;
    const float* offp = op + h * 32;
    const float* awp  = op + 256 + h * 16;
    const float* refp = (z ? ref1 : ref0) + (size_t)bq * 8;
    const short* vb = valb + (size_t)z * MVAL * 256 + (size_t)b * LTOT_C * 256;
    const int co = h * 32 + dl * 4;

    float w16[16];
    float mx = -1e30f;
    #pragma unroll
    for (int i = 0; i < 16; ++i) { w16[i] = awp[i]; mx = fmaxf(mx, w16[i]); }
    float ssum = 0.f;
    #pragma unroll
    for (int i = 0; i < 16; ++i) { w16[i] = __expf(w16[i] - mx); ssum += w16[i]; }
    const float sinv = 1.f / ssum;

    float a0 = 0.f, a1 = 0.f, a2 = 0.f, a3 = 0.f;
#define TAP(cond, ridx, wv)                                                   \
    if (cond) {                                                               \
        const short4 sv = *reinterpret_cast<const short4*>(                   \
            vb + (size_t)(ridx) * 256 + co);                                  \
        a0 += (wv) * bf2f(sv.x); a1 += (wv) * bf2f(sv.y);                     \
        a2 += (wv) * bf2f(sv.z); a3 += (wv) * bf2f(sv.w);                     \
    }
    #pragma unroll
    for (int l = 0; l < 4; ++l) {
        const int Wl = WL[l], Hl = HL[l];
        const float rx = refp[l * 2] * (float)Wl - 0.5f;
        const float ry = refp[l * 2 + 1] * (float)Hl - 0.5f;
        #pragma unroll
        for (int j = 0; j < 2; ++j) {
            const int p = pp * 2 + j;
            const float px = rx + offp[(l * 4 + p) * 2];
            const float py = ry + offp[(l * 4 + p) * 2 + 1];
            const float wgt = w16[l * 4 + p] * sinv;
            const float x0f = floorf(px), y0f = floorf(py);
            const float wx = px - x0f, wy = py - y0f;
            const int x0 = (int)x0f, y0 = (int)y0f;
            const bool xa = (x0 >= 0) & (x0 < Wl);
            const bool xb = (x0 >= -1) & (x0 < Wl - 1);
            const bool ya = (y0 >= 0) & (y0 < Hl);
            const bool yb = (y0 >= -1) & (y0 < Hl - 1);
            const int rbase = ST[l] + y0 * Wl + x0;
            const float w00 = wgt * (1.f - wx) * (1.f - wy);
            const float w10 = wgt * wx * (1.f - wy);
            const float w01 = wgt * (1.f - wx) * wy;
            const float w11 = wgt * wx * wy;
            TAP(ya & xa, rbase, w00)
            TAP(ya & xb, rbase + 1, w10)
            TAP(yb & xa, rbase + Wl, w01)
            TAP(yb & xb, rbase + Wl + 1, w11)
        }
    }
#undef TAP
    a0 += __shfl_xor(a0, 32);
    a1 += __shfl_xor(a1, 32);
    a2 += __shfl_xor(a2, 32);
    a3 += __shfl_xor(a3, 32);
    if (pp == 0) {
        short4 o;
        o.x = f2bf(a0); o.y = f2bf(a1); o.z = f2bf(a2); o.w = f2bf(a3);
        *reinterpret_cast<short4*>(&out[((size_t)z * NTOK + bq) * 256 + co]) = o;
    }
}

extern "C" void kernel_launch(void* const* d_in, const int* in_sizes, int n_in,
                              void* d_out, int out_size, void* d_ws, size_t ws_size,
                              hipStream_t stream) {
    const float* tgt[2] = {(const float*)d_in[0], (const float*)d_in[1]};
    const float* pos[2] = {(const float*)d_in[2], (const float*)d_in[3]};
    const float* ref[2] = {(const float*)d_in[4], (const float*)d_in[5]};
    const float* src[2] = {(const float*)d_in[6], (const float*)d_in[7]};
    const float* sa_in_w  = (const float*)d_in[8];
    const float* sa_in_b  = (const float*)d_in[9];
    const float* sa_out_w = (const float*)d_in[10];
    const float* sa_out_b = (const float*)d_in[11];
    const float* ln_w = (const float*)d_in[12];
    const float* ln_b = (const float*)d_in[13];
    const float* ffn_w1 = (const float*)d_in[14];
    const float* ffn_b1 = (const float*)d_in[15];
    const float* ffn_w2 = (const float*)d_in[16];
    const float* ffn_b2 = (const float*)d_in[17];
    const float* val_w = (const float*)d_in[18];
    const float* val_b = (const float*)d_in[19];
    const float* off_w = (const float*)d_in[20];
    const float* off_b = (const float*)d_in[21];
    const float* aw_w = (const float*)d_in[22];
    const float* aw_b = (const float*)d_in[23];
    const float* cout_w = (const float*)d_in[24];
    const float* cout_b = (const float*)d_in[25];

    char* base = (char*)d_ws;
    size_t off = 0;
    auto alloc = [&](size_t bytes) -> char* {
        char* p = base + off;
        off += (bytes + 255) & ~(size_t)255;
        return p;
    };
    short* wbf   = (short*)alloc((size_t)2031616 * 2);
    float* baw   = (float*)alloc(768 * 4);
    short* qb_bf = (short*)alloc((size_t)2 * STOK * 2);
    short* tgtb  = (short*)alloc((size_t)2 * STOK * 2);
    float* qkv   = (float*)alloc((size_t)2 * 921600 * 4);
    short* attno = (short*)alloc((size_t)2 * STOK * 2);
    float* presum= (float*)alloc((size_t)2 * STOK * 4);
    short* qc_bf = (short*)alloc((size_t)2 * STOK * 2);
    float* tgt2T = (float*)alloc((size_t)STOK * 4);
    float* oawb  = (float*)alloc((size_t)2 * NTOK * 384 * 4);
    short* valb  = (short*)alloc((size_t)2 * MVAL * 256 * 2);
    short* samp  = (short*)alloc((size_t)2 * STOK * 2);
    short* ln1b  = (short*)alloc((size_t)2 * STOK * 2);
    float* ln1f  = (float*)alloc((size_t)2 * STOK * 4);
    short* ffnh  = (short*)alloc((size_t)2 * NTOK * 1024 * 2);
    float* ffny  = (float*)alloc((size_t)2 * STOK * 4);

    // weight sub-offsets (elements)
    short* sa_in_bf  = wbf + 0;        // 393216
    short* sa_out_bf = wbf + 393216;   // 131072
    short* ffn1_bf   = wbf + 524288;   // 524288
    short* ffn2_bf   = wbf + 1048576;  // 524288
    short* val_bf    = wbf + 1572864;  // 131072
    short* cout_bf   = wbf + 1703936;  // 131072
    short* oaw_bf    = wbf + 1835008;  // 196608 = 2 x (off 65536 + aw 32768)

    float* out0 = (float*)d_out;
    float* out1 = out0 + STOK;
    float* out2 = out1 + STOK;   // F_RGB = t2_RGB
    float* out3 = out2 + STOK;   // F_T

    const dim3 b256(256);

    // 1. weights -> bf16 + activation prep (combined, 12 tasks)
    PrepArgs pa;
    pa.s[0] = sa_in_w;        pa.d[0] = sa_in_bf;       pa.n[0] = 393216;
    pa.s[1] = sa_out_w;       pa.d[1] = sa_out_bf;      pa.n[1] = 131072;
    pa.s[2] = ffn_w1;         pa.d[2] = ffn1_bf;        pa.n[2] = 524288;
    pa.s[3] = ffn_w2;         pa.d[3] = ffn2_bf;        pa.n[3] = 524288;
    pa.s[4] = val_w;          pa.d[4] = val_bf;         pa.n[4] = 131072;
    pa.s[5] = cout_w;         pa.d[5] = cout_bf;        pa.n[5] = 131072;
    pa.s[6] = off_w;          pa.d[6] = oaw_bf;         pa.n[6] = 65536;
    pa.s[7] = aw_w;           pa.d[7] = oaw_bf + 65536; pa.n[7] = 32768;
    pa.s[8] = off_w + 65536;  pa.d[8] = oaw_bf + 98304; pa.n[8] = 65536;
    pa.s[9] = aw_w + 32768;   pa.d[9] = oaw_bf + 163840;pa.n[9] = 32768;
    pa.tgt0 = tgt[0]; pa.tgt1 = tgt[1]; pa.pos0 = pos[0]; pa.pos1 = pos[1];
    pa.qb_bf = qb_bf; pa.tgtb = tgtb;
    pa.off_b = off_b; pa.aw_b = aw_b; pa.baw = baw;
    prep_all<<<dim3(150, 12), b256, 0, stream>>>(pa);

    // 2. merged: in-proj (228 blocks) + value projections (4456 blocks)
    val_inproj<<<dim3(4684), b256, 0, stream>>>(
        src[1], src[0], val_bf, val_b, valb,
        qb_bf, tgtb, sa_in_bf, sa_in_b, qkv);

    // 3. attention -> attno bf16
    attn2_kernel<<<dim3(10, 32, 2), b256, 0, stream>>>(qkv, attno);

    // 4. out-proj + residual(tgt) -> presum fp32
    gemm_bf16<true, false, false, 64, 4><<<dim3(2, 19, 2), b256, 0, stream>>>(
        attno, (size_t)STOK, 256, sa_out_bf, 65536, 256, sa_out_b, 256,
        tgt[0], tgt[1], 256, presum, (size_t)STOK, 256, NTOK);

    // 5. norm2 + qc=bf16(LN+pos) + tgt2T
    ln2_fused<<<dim3(NTOK, 2), b256, 0, stream>>>(presum, pos[0], pos[1], ln_w, ln_b, qc_bf, tgt2T);

    // 6. fused offsets+aw logits (N=384) -> oawb
    gemm_bf16<false, false, false, 64, 4><<<dim3(3, 19, 2), b256, 0, stream>>>(
        qc_bf, (size_t)STOK, 256, oaw_bf, 98304, 256, baw, 384,
        nullptr, nullptr, 0, oawb, (size_t)NTOK * 384, 384, NTOK);

    // 7. sampling (fused softmax) -> samp bf16
    sample_kernel<<<dim3(600, 2), b256, 0, stream>>>(valb, oawb, ref[0], ref[1], samp);

    // 8. cout -> out2/out3 (t2_RGB / t2_T)
    gemm_bf16<false, false, false, 64, 4><<<dim3(2, 19, 2), b256, 0, stream>>>(
        samp, (size_t)STOK, 256, cout_bf, 65536, 256, cout_b, 256,
        nullptr, nullptr, 0, out2, (size_t)STOK, 256, NTOK);

    // 9. norm1 (cross residuals fused)
    ln1_fused<<<dim3(NTOK, 2), b256, 0, stream>>>(tgt2T, out2, out3, ln_w, ln_b, ln1b, ln1f);

    // 10. FFN1 (ReLU, bf16 out)
    gemm_bf16<false, true, true, 64, 4><<<dim3(8, 19, 2), b256, 0, stream>>>(
        ln1b, (size_t)STOK, 256, ffn1_bf, 262144, 256, ffn_b1, 1024,
        nullptr, nullptr, 0, ffnh, (size_t)NTOK * 1024, 1024, NTOK);

    // 11. FFN2 + residual(ln1f) -> ffny fp32
    gemm_bf16<true, false, false, 64, 16><<<dim3(2, 19, 2), b256, 0, stream>>>(
        ffnh, (size_t)NTOK * 1024, 1024, ffn2_bf, 262144, 1024, ffn_b2, 256,
        ln1f, ln1f + STOK, 256, ffny, (size_t)STOK, 256, NTOK);

    // 12. norm3 -> out0/out1
    ln3_kernel<<<dim3(NTOK, 2), b256, 0, stream>>>(ffny, ln_w, ln_b, out0, out1);
}

// Round 17
// 179.268 us; speedup vs baseline: 1.2423x; 1.0533x over previous
//
#include <hip/hip_runtime.h>
#include <hip/hip_bf16.h>
#include <cstddef>
#include <math.h>

#define NTOK 1200          // B*NQ = 4*300
#define LTOT_C 17821
#define MVAL 71284         // B*LTOT
#define STOK (NTOK * 256)  // 307200

typedef __attribute__((ext_vector_type(8))) short bhalf8;
typedef __attribute__((ext_vector_type(4))) float f32x4;

static __device__ __forceinline__ short f2bf(float f) {
    unsigned u = __builtin_bit_cast(unsigned, f);
    u += 0x7fffu + ((u >> 16) & 1u);   // RNE
    return (short)(u >> 16);
}
static __device__ __forceinline__ float bf2f(short s) {
    unsigned u = ((unsigned)(unsigned short)s) << 16;
    return __builtin_bit_cast(float, u);
}
static __device__ __forceinline__ bhalf8 cvt8(float4 a, float4 b) {
    bhalf8 h;
    h[0] = f2bf(a.x); h[1] = f2bf(a.y); h[2] = f2bf(a.z); h[3] = f2bf(a.w);
    h[4] = f2bf(b.x); h[5] = f2bf(b.y); h[6] = f2bf(b.z); h[7] = f2bf(b.w);
    return h;
}
// async global -> LDS, 16B per lane; lds dest is wave-uniform base + lane*16
static __device__ __forceinline__ void gload_lds16(const void* g, void* l) {
    __builtin_amdgcn_global_load_lds(
        (const __attribute__((address_space(1))) void*)g,
        (__attribute__((address_space(3))) void*)l, 16, 0, 0);
}

// ---------------- combined weight-convert (tasks 0-9) + activation prep (tasks 10-11) ----
struct PrepArgs {
    const float* s[10]; short* d[10]; int n[10];
    const float* tgt0; const float* tgt1; const float* pos0; const float* pos1;
    short* qb_bf; short* tgtb;
    const float* off_b; const float* aw_b; float* baw;
};
__global__ __launch_bounds__(256) void prep_all(PrepArgs a) {
    const int task = blockIdx.y;
    if (task < 10) {
        const float* s = a.s[task];
        short* d = a.d[task];
        const int n = a.n[task];
        for (int base = (blockIdx.x * 256 + threadIdx.x) * 8; base < n;
             base += gridDim.x * 256 * 8) {
            const float4 f0 = *reinterpret_cast<const float4*>(s + base);
            const float4 f1 = *reinterpret_cast<const float4*>(s + base + 4);
            *reinterpret_cast<bhalf8*>(d + base) = cvt8(f0, f1);
        }
        return;
    }
    const int z = task - 10;
    if (blockIdx.x == 0 && z == 0) {
        for (int i = threadIdx.x; i < 768; i += 256) {
            const int zz = i / 384, j = i - zz * 384;
            a.baw[i] = (j < 256) ? a.off_b[zz * 256 + j] : a.aw_b[zz * 128 + (j - 256)];
        }
    }
    const float* tg = z ? a.tgt1 : a.tgt0;
    const float* ps = z ? a.pos1 : a.pos0;
    const int base = (blockIdx.x * 256 + threadIdx.x) * 8;
    if (base >= STOK) return;
    const float4 t0 = *reinterpret_cast<const float4*>(tg + base);
    const float4 t1 = *reinterpret_cast<const float4*>(tg + base + 4);
    const float4 p0 = *reinterpret_cast<const float4*>(ps + base);
    const float4 p1 = *reinterpret_cast<const float4*>(ps + base + 4);
    float4 s0 = make_float4(t0.x + p0.x, t0.y + p0.y, t0.z + p0.z, t0.w + p0.w);
    float4 s1 = make_float4(t1.x + p1.x, t1.y + p1.y, t1.z + p1.z, t1.w + p1.w);
    *reinterpret_cast<bhalf8*>(a.qb_bf + (size_t)z * STOK + base) = cvt8(s0, s1);
    *reinterpret_cast<bhalf8*>(a.tgtb + (size_t)z * STOK + base) = cvt8(t0, t1);
}

// ---------------- merged kernel: in-proj blocks (0..227) + value projection (228..4683) ---
// Both branches use the single-A-buffer two-barrier reg-commit schedule -> LDS 40 KB
// (As 8 KB + Bs 2x16 KB) -> 4 blocks/CU.  val gets bijective XCD chunking.
__global__ __launch_bounds__(256) void val_inproj(
    const float* __restrict__ A0, const float* __restrict__ A1,
    const short* __restrict__ val_bf, const float* __restrict__ val_b,
    short* __restrict__ valb,
    const short* __restrict__ qb_bf, const short* __restrict__ tgtb,
    const short* __restrict__ sa_in_bf, const float* __restrict__ sa_in_b,
    float* __restrict__ qkv)
{
    __shared__ alignas(16) short As[64 * 64];         // 8 KB (single buffer)
    __shared__ alignas(16) short Bs[2][128 * 64];     // 32 KB
    const int t = threadIdx.x;
    const int wave = t >> 6, lane = t & 63;
    const int l15 = lane & 15, l4 = lane >> 4;
    const int wr = wave >> 1, wc = wave & 1;
    const int nr8 = lane >> 3, q8 = lane & 7;
    const int bi = blockIdx.x;

    if (bi >= 228) {
        // ---------------- value projection (r12-proven) ----------------
        const int i = bi - 228;                     // 0..4455 = 8*557
        const int widx = (i & 7) * 557 + (i >> 3);  // bijective XCD chunking
        const int x = widx & 1;
        const int yz = widx >> 1;
        const int z = yz / 1114;
        const int y = yz - z * 1114;
        const float* A = z ? A1 : A0;
        const short* W = val_bf + (size_t)z * 65536;
        const float* bz = val_b + z * 256;
        short* Cz = valb + (size_t)z * MVAL * 256;
        const int bm = y * 64, bn = x * 128;
        f32x4 acc[2][4] = {};

        auto stageW = [&](int k0, int buf) {
            #pragma unroll
            for (int ii = 0; ii < 4; ++ii) {
                const int c = wave * 4 + ii;
                const int n = c * 8 + nr8;
                gload_lds16(W + (size_t)(bn + n) * 256 + k0 + ((q8 ^ nr8) << 3),
                            (char*)&Bs[buf][0] + c * 1024);
            }
        };
        float4 paf[2][2];
        auto issueA = [&](int k0) {
            #pragma unroll
            for (int ii = 0; ii < 2; ++ii) {
                const int G = t + ii * 256;
                const int m = G >> 3, g = G & 7;
                const int row = min(bm + m, MVAL - 1);
                const float* s = A + (size_t)row * 256 + k0 + g * 8;
                paf[ii][0] = *reinterpret_cast<const float4*>(s);
                paf[ii][1] = *reinterpret_cast<const float4*>(s + 4);
            }
        };
        auto commitA = [&]() {
            #pragma unroll
            for (int ii = 0; ii < 2; ++ii) {
                const int G = t + ii * 256;
                const int m = G >> 3, g = G & 7;
                *reinterpret_cast<bhalf8*>(&As[m * 64 + ((g ^ (m & 7)) << 3)]) =
                    cvt8(paf[ii][0], paf[ii][1]);
            }
        };
        auto compute = [&](int wbuf) {
            #pragma unroll
            for (int kf = 0; kf < 2; ++kf) {
                bhalf8 af[2], bfv[4];
                #pragma unroll
                for (int mf = 0; mf < 2; ++mf) {
                    const int m = wr * 32 + (mf << 4) + l15;
                    const int g = ((kf << 2) + l4) ^ (m & 7);
                    af[mf] = *reinterpret_cast<const bhalf8*>(&As[m * 64 + (g << 3)]);
                }
                #pragma unroll
                for (int nf = 0; nf < 4; ++nf) {
                    const int n = (wc << 6) + (nf << 4) + l15;
                    const int g = ((kf << 2) + l4) ^ (n & 7);
                    bfv[nf] = *reinterpret_cast<const bhalf8*>(&Bs[wbuf][n * 64 + (g << 3)]);
                }
                #pragma unroll
                for (int mf = 0; mf < 2; ++mf)
                    #pragma unroll
                    for (int nf = 0; nf < 4; ++nf)
                        acc[mf][nf] = __builtin_amdgcn_mfma_f32_16x16x32_bf16(
                            af[mf], bfv[nf], acc[mf][nf], 0, 0, 0);
            }
        };

        issueA(0);
        stageW(0, 0);
        commitA();
        __syncthreads();
        #pragma unroll
        for (int ks = 0; ks < 4; ++ks) {
            const int cur = ks & 1, nxt = cur ^ 1;
            if (ks + 1 < 4) {
                issueA((ks + 1) << 6);
                stageW((ks + 1) << 6, nxt);
            }
            compute(cur);
            if (ks + 1 < 4) {
                __syncthreads();
                commitA();
                __syncthreads();
            }
        }

        float br[4];
        #pragma unroll
        for (int nf = 0; nf < 4; ++nf) br[nf] = bz[bn + (wc << 6) + (nf << 4) + l15];
        #pragma unroll
        for (int mf = 0; mf < 2; ++mf) {
            #pragma unroll
            for (int j = 0; j < 4; ++j) {
                const int row = bm + wr * 32 + (mf << 4) + (l4 << 2) + j;
                if (row >= MVAL) continue;
                const int colbase = bn + (wc << 6);
                #pragma unroll
                for (int nf = 0; nf < 4; ++nf)
                    Cz[(size_t)row * 256 + colbase + (nf << 4) + l15] =
                        f2bf(acc[mf][nf][j] + br[nf]);
            }
        }
    } else {
        // ------- merged in-proj (BM=64, NK=4, N=768), reg-staged bf16 A, single A buffer --
        const int z = bi / 114;
        const int r = bi - z * 114;
        const int x = r / 19;           // 0..5
        const int y = r - x * 19;       // 0..18
        const short* Abase = ((x < 4) ? qb_bf : tgtb) + (size_t)z * STOK;
        const short* W = sa_in_bf + (size_t)z * 196608;
        const float* bz = sa_in_b + z * 768;
        const int bm = y * 64, bn = x * 128;
        f32x4 acc[2][4] = {};

        auto stageW = [&](int k0, int buf) {
            #pragma unroll
            for (int ii = 0; ii < 4; ++ii) {
                const int c = wave * 4 + ii;
                const int n = c * 8 + nr8;
                gload_lds16(W + (size_t)(bn + n) * 256 + k0 + ((q8 ^ nr8) << 3),
                            (char*)&Bs[buf][0] + c * 1024);
            }
        };
        bhalf8 pab[2];
        auto issueA = [&](int k0) {
            #pragma unroll
            for (int ii = 0; ii < 2; ++ii) {
                const int G = t + ii * 256;
                const int m = G >> 3, g = G & 7;
                const int row = min(bm + m, NTOK - 1);
                pab[ii] = *reinterpret_cast<const bhalf8*>(
                    Abase + (size_t)row * 256 + k0 + g * 8);
            }
        };
        auto commitA = [&]() {
            #pragma unroll
            for (int ii = 0; ii < 2; ++ii) {
                const int G = t + ii * 256;
                const int m = G >> 3, g = G & 7;
                *reinterpret_cast<bhalf8*>(&As[m * 64 + ((g ^ (m & 7)) << 3)]) = pab[ii];
            }
        };
        auto compute = [&](int wbuf) {
            #pragma unroll
            for (int kf = 0; kf < 2; ++kf) {
                bhalf8 af[2], bfv[4];
                #pragma unroll
                for (int mf = 0; mf < 2; ++mf) {
                    const int m = wr * 32 + (mf << 4) + l15;
                    const int g = ((kf << 2) + l4) ^ (m & 7);
                    af[mf] = *reinterpret_cast<const bhalf8*>(&As[m * 64 + (g << 3)]);
                }
                #pragma unroll
                for (int nf = 0; nf < 4; ++nf) {
                    const int n = (wc << 6) + (nf << 4) + l15;
                    const int g = ((kf << 2) + l4) ^ (n & 7);
                    bfv[nf] = *reinterpret_cast<const bhalf8*>(&Bs[wbuf][n * 64 + (g << 3)]);
                }
                #pragma unroll
                for (int mf = 0; mf < 2; ++mf)
                    #pragma unroll
                    for (int nf = 0; nf < 4; ++nf)
                        acc[mf][nf] = __builtin_amdgcn_mfma_f32_16x16x32_bf16(
                            af[mf], bfv[nf], acc[mf][nf], 0, 0, 0);
            }
        };

        issueA(0);
        stageW(0, 0);
        commitA();
        __syncthreads();
        #pragma unroll
        for (int ks = 0; ks < 4; ++ks) {
            const int cur = ks & 1, nxt = cur ^ 1;
            if (ks + 1 < 4) {
                issueA((ks + 1) << 6);
                stageW((ks + 1) << 6, nxt);
            }
            compute(cur);
            if (ks + 1 < 4) {
                __syncthreads();
                commitA();
                __syncthreads();
            }
        }

        float* Cz = qkv + (size_t)z * 921600;
        float br[4];
        #pragma unroll
        for (int nf = 0; nf < 4; ++nf) br[nf] = bz[bn + (wc << 6) + (nf << 4) + l15];
        #pragma unroll
        for (int mf = 0; mf < 2; ++mf) {
            #pragma unroll
            for (int j = 0; j < 4; ++j) {
                const int row = bm + wr * 32 + (mf << 4) + (l4 << 2) + j;
                if (row >= NTOK) continue;
                const int colbase = bn + (wc << 6);
                #pragma unroll
                for (int nf = 0; nf < 4; ++nf)
                    Cz[(size_t)row * 768 + colbase + (nf << 4) + l15] = acc[mf][nf][j] + br[nf];
            }
        }
    }
}

// ---------------- unified bf16 MFMA GEMM (bf16 A): async gload_lds, dbuf ----------------
template<bool HASRES, bool RELU, bool OUT_BF16, int BM, int NK>
__global__ __launch_bounds__(256) void gemm_bf16(
    const short* __restrict__ Av, size_t aStrideZ, int lda,
    const short* __restrict__ Wv, size_t wStrideZ, int ldw,
    const float* __restrict__ bias, size_t biasStrideZ,
    const float* __restrict__ Res0, const float* __restrict__ Res1, int ldr,
    void* __restrict__ Cv, size_t cStrideZ, int ldc,
    int M)
{
    constexpr int MFR = BM / 32;
    constexpr int ACW = BM / 32;
    __shared__ alignas(16) short As[2][BM * 64];
    __shared__ alignas(16) short Bs[2][128 * 64];
    const int z = blockIdx.z;
    const short* W = Wv + (size_t)z * wStrideZ;
    const float* bz = bias + (size_t)z * biasStrideZ;
    const int t = threadIdx.x;
    const int wave = t >> 6, lane = t & 63;
    const int l15 = lane & 15, l4 = lane >> 4;
    const int wr = wave >> 1, wc = wave & 1;
    const int bm = blockIdx.y * BM, bn = blockIdx.x * 128;
    f32x4 acc[MFR][4] = {};

    const int nr8 = lane >> 3, q8 = lane & 7;
    auto stageW = [&](int k0, int buf) {
        #pragma unroll
        for (int i = 0; i < 4; ++i) {
            const int c = wave * 4 + i;
            const int n = c * 8 + nr8;
            gload_lds16(W + (size_t)(bn + n) * ldw + k0 + ((q8 ^ nr8) << 3),
                        (char*)&Bs[buf][0] + c * 1024);
        }
    };
    auto stageA = [&](int k0, int buf) {
        #pragma unroll
        for (int i = 0; i < ACW; ++i) {
            const int c = wave * ACW + i;
            const int m = c * 8 + nr8;
            const int row = min(bm + m, M - 1);
            gload_lds16(Av + (size_t)z * aStrideZ + (size_t)row * lda + k0 + ((q8 ^ (m & 7)) << 3),
                        (char*)&As[buf][0] + c * 1024);
        }
    };
    auto compute = [&](int buf) {
        #pragma unroll
        for (int kf = 0; kf < 2; ++kf) {
            bhalf8 af[MFR], bfv[4];
            #pragma unroll
            for (int mf = 0; mf < MFR; ++mf) {
                const int m = wr * (BM / 2) + (mf << 4) + l15;
                const int g = ((kf << 2) + l4) ^ (m & 7);
                af[mf] = *reinterpret_cast<const bhalf8*>(&As[buf][m * 64 + (g << 3)]);
            }
            #pragma unroll
            for (int nf = 0; nf < 4; ++nf) {
                const int n = (wc << 6) + (nf << 4) + l15;
                const int g = ((kf << 2) + l4) ^ (n & 7);
                bfv[nf] = *reinterpret_cast<const bhalf8*>(&Bs[buf][n * 64 + (g << 3)]);
            }
            #pragma unroll
            for (int mf = 0; mf < MFR; ++mf)
                #pragma unroll
                for (int nf = 0; nf < 4; ++nf)
                    acc[mf][nf] = __builtin_amdgcn_mfma_f32_16x16x32_bf16(
                        af[mf], bfv[nf], acc[mf][nf], 0, 0, 0);
        }
    };

    stageA(0, 0);
    stageW(0, 0);
    __syncthreads();
    #pragma unroll
    for (int ks = 0; ks < NK; ++ks) {
        const int cur = ks & 1, nxt = cur ^ 1;
        if (ks + 1 < NK) {
            stageA((ks + 1) << 6, nxt);
            stageW((ks + 1) << 6, nxt);
        }
        compute(cur);
        __syncthreads();
    }

    const float* Rz = HASRES ? (z ? Res1 : Res0) : nullptr;
    float br[4];
    #pragma unroll
    for (int nf = 0; nf < 4; ++nf) br[nf] = bz[bn + (wc << 6) + (nf << 4) + l15];
    #pragma unroll
    for (int mf = 0; mf < MFR; ++mf) {
        #pragma unroll
        for (int j = 0; j < 4; ++j) {
            const int row = bm + wr * (BM / 2) + (mf << 4) + (l4 << 2) + j;
            if (row >= M) continue;
            const int colbase = bn + (wc << 6);
            #pragma unroll
            for (int nf = 0; nf < 4; ++nf) {
                const int col = colbase + (nf << 4) + l15;
                float v = acc[mf][nf][j] + br[nf];
                if (HASRES) v += Rz[(size_t)row * ldr + col];
                if (RELU) v = fmaxf(v, 0.f);
                if (OUT_BF16)
                    ((short*)Cv + (size_t)z * cStrideZ)[(size_t)row * ldc + col] = f2bf(v);
                else
                    ((float*)Cv + (size_t)z * cStrideZ)[(size_t)row * ldc + col] = v;
            }
        }
    }
}

// ---------------- self-attention: key-parallel online softmax, bf16 out ----------------
__global__ __launch_bounds__(256) void attn2_kernel(
    const float* __restrict__ qkv_base, short* __restrict__ out_base)
{
    const float scale = 0.17677669529663687f;  // 1/sqrt(32)
    const float* qkv = qkv_base + (size_t)blockIdx.z * 921600;
    short* outp = out_base + (size_t)blockIdx.z * STOK;
    const int b = blockIdx.y >> 3, h = blockIdx.y & 7;
    const int t = threadIdx.x;
    const int ql = t & 31;
    const int kg = t >> 5;
    const int q = blockIdx.x * 32 + ql;
    const bool act = q < 300;
    const float* base = qkv + (size_t)b * 300 * 768;

    float qreg[32];
    if (act) {
        const float4* qp = reinterpret_cast<const float4*>(base + (size_t)q * 768 + h * 32);
        #pragma unroll
        for (int d4 = 0; d4 < 8; ++d4) {
            const float4 v = qp[d4];
            qreg[d4 * 4 + 0] = v.x; qreg[d4 * 4 + 1] = v.y;
            qreg[d4 * 4 + 2] = v.z; qreg[d4 * 4 + 3] = v.w;
        }
    }
    __shared__ float Ks[64][32];
    __shared__ float Vs[64][32];
    float m = -1e30f, l = 0.f, o[32];
    #pragma unroll
    for (int d = 0; d < 32; ++d) o[d] = 0.f;

    for (int k0 = 0; k0 < 300; k0 += 64) {
        const int cnt = min(64, 300 - k0);
        __syncthreads();
        for (int i = t; i < cnt * 32; i += 256) {
            const int kr = i >> 5, d = i & 31;
            Ks[kr][d] = base[(size_t)(k0 + kr) * 768 + 256 + h * 32 + d];
            Vs[kr][d] = base[(size_t)(k0 + kr) * 768 + 512 + h * 32 + d];
        }
        __syncthreads();
        if (act) {
            for (int kk = kg; kk < cnt; kk += 8) {
                const float4* krow = reinterpret_cast<const float4*>(&Ks[kk][0]);
                float s = 0.f;
                #pragma unroll
                for (int d4 = 0; d4 < 8; ++d4) {
                    const float4 kv = krow[d4];
                    s += qreg[d4 * 4 + 0] * kv.x + qreg[d4 * 4 + 1] * kv.y
                       + qreg[d4 * 4 + 2] * kv.z + qreg[d4 * 4 + 3] * kv.w;
                }
                s *= scale;
                const float4* vrow = reinterpret_cast<const float4*>(&Vs[kk][0]);
                if (s <= m) {
                    const float e = __expf(s - m);
                    l += e;
                    #pragma unroll
                    for (int d4 = 0; d4 < 8; ++d4) {
                        const float4 vv = vrow[d4];
                        o[d4 * 4 + 0] += e * vv.x; o[d4 * 4 + 1] += e * vv.y;
                        o[d4 * 4 + 2] += e * vv.z; o[d4 * 4 + 3] += e * vv.w;
                    }
                } else {
                    const float c = __expf(m - s);
                    l = l * c + 1.f;
                    #pragma unroll
                    for (int d4 = 0; d4 < 8; ++d4) {
                        const float4 vv = vrow[d4];
                        o[d4 * 4 + 0] = o[d4 * 4 + 0] * c + vv.x;
                        o[d4 * 4 + 1] = o[d4 * 4 + 1] * c + vv.y;
                        o[d4 * 4 + 2] = o[d4 * 4 + 2] * c + vv.z;
                        o[d4 * 4 + 3] = o[d4 * 4 + 3] * c + vv.w;
                    }
                    m = s;
                }
            }
        }
    }
    __shared__ float pm[32][8];
    __shared__ float pl[32][8];
    __shared__ float po[8][32][33];
    pm[ql][kg] = m; pl[ql][kg] = l;
    #pragma unroll
    for (int d = 0; d < 32; ++d) po[kg][d][ql] = o[d];
    __syncthreads();
    if (kg == 0) {
        float M = pm[ql][0];
        #pragma unroll
        for (int i = 1; i < 8; ++i) M = fmaxf(M, pm[ql][i]);
        float L = 0.f;
        #pragma unroll
        for (int i = 0; i < 8; ++i) L += pl[ql][i] * __expf(pm[ql][i] - M);
        const float invL = 1.f / L;
        #pragma unroll
        for (int i = 0; i < 8; ++i) pm[ql][i] = __expf(pm[ql][i] - M) * invL;
    }
    __syncthreads();
    if (act) {
        #pragma unroll
        for (int dd = 0; dd < 4; ++dd) {
            const int d = kg * 4 + dd;
            float v = 0.f;
            #pragma unroll
            for (int i = 0; i < 8; ++i) v += pm[ql][i] * po[i][d][ql];
            outp[((size_t)b * 300 + q) * 256 + h * 32 + d] = f2bf(v);
        }
    }
}

// ---------------- LN block-reduce body ----------------
#define LN_BODY(vexpr, widx)                                                  \
    const int row = blockIdx.x, t = threadIdx.x, z = blockIdx.y;              \
    (void)z;                                                                  \
    const int i = row * 256 + t;                                              \
    const float v = (vexpr);                                                  \
    __shared__ float r1[4], r2[4];                                            \
    float s = v;                                                              \
    _Pragma("unroll")                                                         \
    for (int o = 32; o; o >>= 1) s += __shfl_xor(s, o);                       \
    if ((t & 63) == 0) r1[t >> 6] = s;                                        \
    __syncthreads();                                                          \
    const float mean = (r1[0] + r1[1] + r1[2] + r1[3]) * (1.f / 256.f);       \
    const float dd = v - mean;                                                \
    float sq = dd * dd;                                                       \
    _Pragma("unroll")                                                         \
    for (int o = 32; o; o >>= 1) sq += __shfl_xor(sq, o);                     \
    if ((t & 63) == 0) r2[t >> 6] = sq;                                       \
    __syncthreads();                                                          \
    const float var = (r2[0] + r2[1] + r2[2] + r2[3]) * (1.f / 256.f);        \
    const float y = dd * rsqrtf(var + 1e-5f) * ln_w[(widx) * 256 + t]         \
                    + ln_b[(widx) * 256 + t];

__global__ __launch_bounds__(256) void ln2_fused(
    const float* __restrict__ presum, const float* __restrict__ pos0,
    const float* __restrict__ pos1, const float* __restrict__ ln_w,
    const float* __restrict__ ln_b, short* __restrict__ qc_bf,
    float* __restrict__ tgt2T)
{
    LN_BODY(presum[(size_t)z * STOK + i], z * 3 + 1)
    const float* pos = z ? pos1 : pos0;
    qc_bf[(size_t)z * STOK + i] = f2bf(y + pos[i]);
    if (z == 1) tgt2T[i] = y;
}

__global__ __launch_bounds__(256) void ln1_fused(
    const float* __restrict__ tgt2T, const float* __restrict__ out2,
    const float* __restrict__ out3, const float* __restrict__ ln_w,
    const float* __restrict__ ln_b, short* __restrict__ ln1b,
    float* __restrict__ ln1f)
{
    LN_BODY(tgt2T[row * 256 + t] + out2[row * 256 + t] + (z ? out3[row * 256 + t] : 0.f), z * 3 + 0)
    ln1b[(size_t)z * STOK + i] = f2bf(y);
    ln1f[(size_t)z * STOK + i] = y;
}

__global__ __launch_bounds__(256) void ln3_kernel(
    const float* __restrict__ ffny, const float* __restrict__ ln_w,
    const float* __restrict__ ln_b, float* __restrict__ o0,
    float* __restrict__ o1)
{
    LN_BODY(ffny[(size_t)z * STOK + i], z * 3 + 2)
    (z ? o1 : o0)[i] = y;
}

// ---------------- deformable sampling: short4 gathers, wave=(q, head-half) ----------------
__global__ __launch_bounds__(256) void sample_kernel(
    const short* __restrict__ valb, const float* __restrict__ oaw,
    const float* __restrict__ ref0, const float* __restrict__ ref1,
    short* __restrict__ out)
{
    const int HL[4] = {100, 50, 25, 13};
    const int WL[4] = {134, 67, 34, 17};
    const int ST[4] = {0, 13400, 16750, 17600};
    const int z = blockIdx.y;
    const int t = threadIdx.x;
    const int wave = t >> 6, lane = t & 63;
    const int qi = wave >> 1, hh = wave & 1;
    const int pp = lane >> 5, h4 = (lane >> 3) & 3, dl = lane & 7;
    const int h = hh * 4 + h4;
    const int bq = blockIdx.x * 2 + qi;
    const int b = bq / 300;
    const float* op = oaw + ((size_t)z * NTOK + bq) * 384;
    const float* offp = op + h * 32;
    const float* awp  = op + 256 + h * 16;
    const float* refp = (z ? ref1 : ref0) + (size_t)bq * 8;
    const short* vb = valb + (size_t)z * MVAL * 256 + (size_t)b * LTOT_C * 256;
    const int co = h * 32 + dl * 4;

    float w16[16];
    float mx = -1e30f;
    #pragma unroll
    for (int i = 0; i < 16; ++i) { w16[i] = awp[i]; mx = fmaxf(mx, w16[i]); }
    float ssum = 0.f;
    #pragma unroll
    for (int i = 0; i < 16; ++i) { w16[i] = __expf(w16[i] - mx); ssum += w16[i]; }
    const float sinv = 1.f / ssum;

    float a0 = 0.f, a1 = 0.f, a2 = 0.f, a3 = 0.f;
#define TAP(cond, ridx, wv)                                                   \
    if (cond) {                                                               \
        const short4 sv = *reinterpret_cast<const short4*>(                   \
            vb + (size_t)(ridx) * 256 + co);                                  \
        a0 += (wv) * bf2f(sv.x); a1 += (wv) * bf2f(sv.y);                     \
        a2 += (wv) * bf2f(sv.z); a3 += (wv) * bf2f(sv.w);                     \
    }
    #pragma unroll
    for (int l = 0; l < 4; ++l) {
        const int Wl = WL[l], Hl = HL[l];
        const float rx = refp[l * 2] * (float)Wl - 0.5f;
        const float ry = refp[l * 2 + 1] * (float)Hl - 0.5f;
        #pragma unroll
        for (int j = 0; j < 2; ++j) {
            const int p = pp * 2 + j;
            const float px = rx + offp[(l * 4 + p) * 2];
            const float py = ry + offp[(l * 4 + p) * 2 + 1];
            const float wgt = w16[l * 4 + p] * sinv;
            const float x0f = floorf(px), y0f = floorf(py);
            const float wx = px - x0f, wy = py - y0f;
            const int x0 = (int)x0f, y0 = (int)y0f;
            const bool xa = (x0 >= 0) & (x0 < Wl);
            const bool xb = (x0 >= -1) & (x0 < Wl - 1);
            const bool ya = (y0 >= 0) & (y0 < Hl);
            const bool yb = (y0 >= -1) & (y0 < Hl - 1);
            const int rbase = ST[l] + y0 * Wl + x0;
            const float w00 = wgt * (1.f - wx) * (1.f - wy);
            const float w10 = wgt * wx * (1.f - wy);
            const float w01 = wgt * (1.f - wx) * wy;
            const float w11 = wgt * wx * wy;
            TAP(ya & xa, rbase, w00)
            TAP(ya & xb, rbase + 1, w10)
            TAP(yb & xa, rbase + Wl, w01)
            TAP(yb & xb, rbase + Wl + 1, w11)
        }
    }
#undef TAP
    a0 += __shfl_xor(a0, 32);
    a1 += __shfl_xor(a1, 32);
    a2 += __shfl_xor(a2, 32);
    a3 += __shfl_xor(a3, 32);
    if (pp == 0) {
        short4 o;
        o.x = f2bf(a0); o.y = f2bf(a1); o.z = f2bf(a2); o.w = f2bf(a3);
        *reinterpret_cast<short4*>(&out[((size_t)z * NTOK + bq) * 256 + co]) = o;
    }
}

extern "C" void kernel_launch(void* const* d_in, const int* in_sizes, int n_in,
                              void* d_out, int out_size, void* d_ws, size_t ws_size,
                              hipStream_t stream) {
    const float* tgt[2] = {(const float*)d_in[0], (const float*)d_in[1]};
    const float* pos[2] = {(const float*)d_in[2], (const float*)d_in[3]};
    const float* ref[2] = {(const float*)d_in[4], (const float*)d_in[5]};
    const float* src[2] = {(const float*)d_in[6], (const float*)d_in[7]};
    const float* sa_in_w  = (const float*)d_in[8];
    const float* sa_in_b  = (const float*)d_in[9];
    const float* sa_out_w = (const float*)d_in[10];
    const float* sa_out_b = (const float*)d_in[11];
    const float* ln_w = (const float*)d_in[12];
    const float* ln_b = (const float*)d_in[13];
    const float* ffn_w1 = (const float*)d_in[14];
    const float* ffn_b1 = (const float*)d_in[15];
    const float* ffn_w2 = (const float*)d_in[16];
    const float* ffn_b2 = (const float*)d_in[17];
    const float* val_w = (const float*)d_in[18];
    const float* val_b = (const float*)d_in[19];
    const float* off_w = (const float*)d_in[20];
    const float* off_b = (const float*)d_in[21];
    const float* aw_w = (const float*)d_in[22];
    const float* aw_b = (const float*)d_in[23];
    const float* cout_w = (const float*)d_in[24];
    const float* cout_b = (const float*)d_in[25];

    char* base = (char*)d_ws;
    size_t off = 0;
    auto alloc = [&](size_t bytes) -> char* {
        char* p = base + off;
        off += (bytes + 255) & ~(size_t)255;
        return p;
    };
    short* wbf   = (short*)alloc((size_t)2031616 * 2);
    float* baw   = (float*)alloc(768 * 4);
    short* qb_bf = (short*)alloc((size_t)2 * STOK * 2);
    short* tgtb  = (short*)alloc((size_t)2 * STOK * 2);
    float* qkv   = (float*)alloc((size_t)2 * 921600 * 4);
    short* attno = (short*)alloc((size_t)2 * STOK * 2);
    float* presum= (float*)alloc((size_t)2 * STOK * 4);
    short* qc_bf = (short*)alloc((size_t)2 * STOK * 2);
    float* tgt2T = (float*)alloc((size_t)STOK * 4);
    float* oawb  = (float*)alloc((size_t)2 * NTOK * 384 * 4);
    short* valb  = (short*)alloc((size_t)2 * MVAL * 256 * 2);
    short* samp  = (short*)alloc((size_t)2 * STOK * 2);
    short* ln1b  = (short*)alloc((size_t)2 * STOK * 2);
    float* ln1f  = (float*)alloc((size_t)2 * STOK * 4);
    short* ffnh  = (short*)alloc((size_t)2 * NTOK * 1024 * 2);
    float* ffny  = (float*)alloc((size_t)2 * STOK * 4);

    // weight sub-offsets (elements)
    short* sa_in_bf  = wbf + 0;        // 393216
    short* sa_out_bf = wbf + 393216;   // 131072
    short* ffn1_bf   = wbf + 524288;   // 524288
    short* ffn2_bf   = wbf + 1048576;  // 524288
    short* val_bf    = wbf + 1572864;  // 131072
    short* cout_bf   = wbf + 1703936;  // 131072
    short* oaw_bf    = wbf + 1835008;  // 196608 = 2 x (off 65536 + aw 32768)

    float* out0 = (float*)d_out;
    float* out1 = out0 + STOK;
    float* out2 = out1 + STOK;   // F_RGB = t2_RGB
    float* out3 = out2 + STOK;   // F_T

    const dim3 b256(256);

    // 1. weights -> bf16 + activation prep (combined, 12 tasks)
    PrepArgs pa;
    pa.s[0] = sa_in_w;        pa.d[0] = sa_in_bf;       pa.n[0] = 393216;
    pa.s[1] = sa_out_w;       pa.d[1] = sa_out_bf;      pa.n[1] = 131072;
    pa.s[2] = ffn_w1;         pa.d[2] = ffn1_bf;        pa.n[2] = 524288;
    pa.s[3] = ffn_w2;         pa.d[3] = ffn2_bf;        pa.n[3] = 524288;
    pa.s[4] = val_w;          pa.d[4] = val_bf;         pa.n[4] = 131072;
    pa.s[5] = cout_w;         pa.d[5] = cout_bf;        pa.n[5] = 131072;
    pa.s[6] = off_w;          pa.d[6] = oaw_bf;         pa.n[6] = 65536;
    pa.s[7] = aw_w;           pa.d[7] = oaw_bf + 65536; pa.n[7] = 32768;
    pa.s[8] = off_w + 65536;  pa.d[8] = oaw_bf + 98304; pa.n[8] = 65536;
    pa.s[9] = aw_w + 32768;   pa.d[9] = oaw_bf + 163840;pa.n[9] = 32768;
    pa.tgt0 = tgt[0]; pa.tgt1 = tgt[1]; pa.pos0 = pos[0]; pa.pos1 = pos[1];
    pa.qb_bf = qb_bf; pa.tgtb = tgtb;
    pa.off_b = off_b; pa.aw_b = aw_b; pa.baw = baw;
    prep_all<<<dim3(150, 12), b256, 0, stream>>>(pa);

    // 2. merged: in-proj (228 blocks) + value projections (4456 blocks), 40 KB LDS
    val_inproj<<<dim3(4684), b256, 0, stream>>>(
        src[1], src[0], val_bf, val_b, valb,
        qb_bf, tgtb, sa_in_bf, sa_in_b, qkv);

    // 3. attention -> attno bf16
    attn2_kernel<<<dim3(10, 32, 2), b256, 0, stream>>>(qkv, attno);

    // 4. out-proj + residual(tgt) -> presum fp32
    gemm_bf16<true, false, false, 64, 4><<<dim3(2, 19, 2), b256, 0, stream>>>(
        attno, (size_t)STOK, 256, sa_out_bf, 65536, 256, sa_out_b, 256,
        tgt[0], tgt[1], 256, presum, (size_t)STOK, 256, NTOK);

    // 5. norm2 + qc=bf16(LN+pos) + tgt2T
    ln2_fused<<<dim3(NTOK, 2), b256, 0, stream>>>(presum, pos[0], pos[1], ln_w, ln_b, qc_bf, tgt2T);

    // 6. fused offsets+aw logits (N=384) -> oawb
    gemm_bf16<false, false, false, 64, 4><<<dim3(3, 19, 2), b256, 0, stream>>>(
        qc_bf, (size_t)STOK, 256, oaw_bf, 98304, 256, baw, 384,
        nullptr, nullptr, 0, oawb, (size_t)NTOK * 384, 384, NTOK);

    // 7. sampling (fused softmax) -> samp bf16
    sample_kernel<<<dim3(600, 2), b256, 0, stream>>>(valb, oawb, ref[0], ref[1], samp);

    // 8. cout -> out2/out3 (t2_RGB / t2_T)
    gemm_bf16<false, false, false, 64, 4><<<dim3(2, 19, 2), b256, 0, stream>>>(
        samp, (size_t)STOK, 256, cout_bf, 65536, 256, cout_b, 256,
        nullptr, nullptr, 0, out2, (size_t)STOK, 256, NTOK);

    // 9. norm1 (cross residuals fused)
    ln1_fused<<<dim3(NTOK, 2), b256, 0, stream>>>(tgt2T, out2, out3, ln_w, ln_b, ln1b, ln1f);

    // 10. FFN1 (ReLU, bf16 out)
    gemm_bf16<false, true, true, 64, 4><<<dim3(8, 19, 2), b256, 0, stream>>>(
        ln1b, (size_t)STOK, 256, ffn1_bf, 262144, 256, ffn_b1, 1024,
        nullptr, nullptr, 0, ffnh, (size_t)NTOK * 1024, 1024, NTOK);

    // 11. FFN2 + residual(ln1f) -> ffny fp32
    gemm_bf16<true, false, false, 64, 16><<<dim3(2, 19, 2), b256, 0, stream>>>(
        ffnh, (size_t)NTOK * 1024, 1024, ffn2_bf, 262144, 1024, ffn_b2, 256,
        ln1f, ln1f + STOK, 256, ffny, (size_t)STOK, 256, NTOK);

    // 12. norm3 -> out0/out1
    ln3_kernel<<<dim3(NTOK, 2), b256, 0, stream>>>(ffny, ln_w, ln_b, out0, out1);
}

// Round 18
// 177.874 us; speedup vs baseline: 1.2520x; 1.0078x over previous
//
#include <hip/hip_runtime.h>
#include <hip/hip_bf16.h>
#include <cstddef>
#include <math.h>

#define NTOK 1200          // B*NQ = 4*300
#define LTOT_C 17821
#define MVAL 71284         // B*LTOT
#define STOK (NTOK * 256)  // 307200

typedef __attribute__((ext_vector_type(8))) short bhalf8;
typedef __attribute__((ext_vector_type(4))) float f32x4;

static __device__ __forceinline__ short f2bf(float f) {
    unsigned u = __builtin_bit_cast(unsigned, f);
    u += 0x7fffu + ((u >> 16) & 1u);   // RNE
    return (short)(u >> 16);
}
static __device__ __forceinline__ float bf2f(short s) {
    unsigned u = ((unsigned)(unsigned short)s) << 16;
    return __builtin_bit_cast(float, u);
}
static __device__ __forceinline__ bhalf8 cvt8(float4 a, float4 b) {
    bhalf8 h;
    h[0] = f2bf(a.x); h[1] = f2bf(a.y); h[2] = f2bf(a.z); h[3] = f2bf(a.w);
    h[4] = f2bf(b.x); h[5] = f2bf(b.y); h[6] = f2bf(b.z); h[7] = f2bf(b.w);
    return h;
}
// async global -> LDS, 16B per lane; lds dest is wave-uniform base + lane*16
static __device__ __forceinline__ void gload_lds16(const void* g, void* l) {
    __builtin_amdgcn_global_load_lds(
        (const __attribute__((address_space(1))) void*)g,
        (__attribute__((address_space(3))) void*)l, 16, 0, 0);
}

// ---------------- combined weight-convert (tasks 0-9) + activation prep (tasks 10-11) ----
struct PrepArgs {
    const float* s[10]; short* d[10]; int n[10];
    const float* tgt0; const float* tgt1; const float* pos0; const float* pos1;
    short* qb_bf; short* tgtb;
    const float* off_b; const float* aw_b; float* baw;
};
__global__ __launch_bounds__(256) void prep_all(PrepArgs a) {
    const int task = blockIdx.y;
    if (task < 10) {
        const float* s = a.s[task];
        short* d = a.d[task];
        const int n = a.n[task];
        for (int base = (blockIdx.x * 256 + threadIdx.x) * 8; base < n;
             base += gridDim.x * 256 * 8) {
            const float4 f0 = *reinterpret_cast<const float4*>(s + base);
            const float4 f1 = *reinterpret_cast<const float4*>(s + base + 4);
            *reinterpret_cast<bhalf8*>(d + base) = cvt8(f0, f1);
        }
        return;
    }
    const int z = task - 10;
    if (blockIdx.x == 0 && z == 0) {
        for (int i = threadIdx.x; i < 768; i += 256) {
            const int zz = i / 384, j = i - zz * 384;
            a.baw[i] = (j < 256) ? a.off_b[zz * 256 + j] : a.aw_b[zz * 128 + (j - 256)];
        }
    }
    const float* tg = z ? a.tgt1 : a.tgt0;
    const float* ps = z ? a.pos1 : a.pos0;
    const int base = (blockIdx.x * 256 + threadIdx.x) * 8;
    if (base >= STOK) return;
    const float4 t0 = *reinterpret_cast<const float4*>(tg + base);
    const float4 t1 = *reinterpret_cast<const float4*>(tg + base + 4);
    const float4 p0 = *reinterpret_cast<const float4*>(ps + base);
    const float4 p1 = *reinterpret_cast<const float4*>(ps + base + 4);
    float4 s0 = make_float4(t0.x + p0.x, t0.y + p0.y, t0.z + p0.z, t0.w + p0.w);
    float4 s1 = make_float4(t1.x + p1.x, t1.y + p1.y, t1.z + p1.z, t1.w + p1.w);
    *reinterpret_cast<bhalf8*>(a.qb_bf + (size_t)z * STOK + base) = cvt8(s0, s1);
    *reinterpret_cast<bhalf8*>(a.tgtb + (size_t)z * STOK + base) = cvt8(t0, t1);
}

// ---------------- merged kernel: in-proj blocks (0..227) + value projection (228..4683) ---
// Both branches use the single-A-buffer two-barrier reg-commit schedule -> LDS 40 KB
// (As 8 KB + Bs 2x16 KB) -> 4 blocks/CU.  val gets bijective XCD chunking.
__global__ __launch_bounds__(256) void val_inproj(
    const float* __restrict__ A0, const float* __restrict__ A1,
    const short* __restrict__ val_bf, const float* __restrict__ val_b,
    short* __restrict__ valb,
    const short* __restrict__ qb_bf, const short* __restrict__ tgtb,
    const short* __restrict__ sa_in_bf, const float* __restrict__ sa_in_b,
    float* __restrict__ qkv)
{
    __shared__ alignas(16) short As[64 * 64];         // 8 KB (single buffer)
    __shared__ alignas(16) short Bs[2][128 * 64];     // 32 KB
    const int t = threadIdx.x;
    const int wave = t >> 6, lane = t & 63;
    const int l15 = lane & 15, l4 = lane >> 4;
    const int wr = wave >> 1, wc = wave & 1;
    const int nr8 = lane >> 3, q8 = lane & 7;
    const int bi = blockIdx.x;

    if (bi >= 228) {
        // ---------------- value projection (r12-proven) ----------------
        const int i = bi - 228;                     // 0..4455 = 8*557
        const int widx = (i & 7) * 557 + (i >> 3);  // bijective XCD chunking
        const int x = widx & 1;
        const int yz = widx >> 1;
        const int z = yz / 1114;
        const int y = yz - z * 1114;
        const float* A = z ? A1 : A0;
        const short* W = val_bf + (size_t)z * 65536;
        const float* bz = val_b + z * 256;
        short* Cz = valb + (size_t)z * MVAL * 256;
        const int bm = y * 64, bn = x * 128;
        f32x4 acc[2][4] = {};

        auto stageW = [&](int k0, int buf) {
            #pragma unroll
            for (int ii = 0; ii < 4; ++ii) {
                const int c = wave * 4 + ii;
                const int n = c * 8 + nr8;
                gload_lds16(W + (size_t)(bn + n) * 256 + k0 + ((q8 ^ nr8) << 3),
                            (char*)&Bs[buf][0] + c * 1024);
            }
        };
        float4 paf[2][2];
        auto issueA = [&](int k0) {
            #pragma unroll
            for (int ii = 0; ii < 2; ++ii) {
                const int G = t + ii * 256;
                const int m = G >> 3, g = G & 7;
                const int row = min(bm + m, MVAL - 1);
                const float* s = A + (size_t)row * 256 + k0 + g * 8;
                paf[ii][0] = *reinterpret_cast<const float4*>(s);
                paf[ii][1] = *reinterpret_cast<const float4*>(s + 4);
            }
        };
        auto commitA = [&]() {
            #pragma unroll
            for (int ii = 0; ii < 2; ++ii) {
                const int G = t + ii * 256;
                const int m = G >> 3, g = G & 7;
                *reinterpret_cast<bhalf8*>(&As[m * 64 + ((g ^ (m & 7)) << 3)]) =
                    cvt8(paf[ii][0], paf[ii][1]);
            }
        };
        auto compute = [&](int wbuf) {
            #pragma unroll
            for (int kf = 0; kf < 2; ++kf) {
                bhalf8 af[2], bfv[4];
                #pragma unroll
                for (int mf = 0; mf < 2; ++mf) {
                    const int m = wr * 32 + (mf << 4) + l15;
                    const int g = ((kf << 2) + l4) ^ (m & 7);
                    af[mf] = *reinterpret_cast<const bhalf8*>(&As[m * 64 + (g << 3)]);
                }
                #pragma unroll
                for (int nf = 0; nf < 4; ++nf) {
                    const int n = (wc << 6) + (nf << 4) + l15;
                    const int g = ((kf << 2) + l4) ^ (n & 7);
                    bfv[nf] = *reinterpret_cast<const bhalf8*>(&Bs[wbuf][n * 64 + (g << 3)]);
                }
                #pragma unroll
                for (int mf = 0; mf < 2; ++mf)
                    #pragma unroll
                    for (int nf = 0; nf < 4; ++nf)
                        acc[mf][nf] = __builtin_amdgcn_mfma_f32_16x16x32_bf16(
                            af[mf], bfv[nf], acc[mf][nf], 0, 0, 0);
            }
        };

        issueA(0);
        stageW(0, 0);
        commitA();
        __syncthreads();
        #pragma unroll
        for (int ks = 0; ks < 4; ++ks) {
            const int cur = ks & 1, nxt = cur ^ 1;
            if (ks + 1 < 4) {
                issueA((ks + 1) << 6);
                stageW((ks + 1) << 6, nxt);
            }
            compute(cur);
            if (ks + 1 < 4) {
                __syncthreads();
                commitA();
                __syncthreads();
            }
        }

        float br[4];
        #pragma unroll
        for (int nf = 0; nf < 4; ++nf) br[nf] = bz[bn + (wc << 6) + (nf << 4) + l15];
        #pragma unroll
        for (int mf = 0; mf < 2; ++mf) {
            #pragma unroll
            for (int j = 0; j < 4; ++j) {
                const int row = bm + wr * 32 + (mf << 4) + (l4 << 2) + j;
                if (row >= MVAL) continue;
                const int colbase = bn + (wc << 6);
                #pragma unroll
                for (int nf = 0; nf < 4; ++nf)
                    Cz[(size_t)row * 256 + colbase + (nf << 4) + l15] =
                        f2bf(acc[mf][nf][j] + br[nf]);
            }
        }
    } else {
        // ------- merged in-proj (BM=64, NK=4, N=768), reg-staged bf16 A, single A buffer --
        const int z = bi / 114;
        const int r = bi - z * 114;
        const int x = r / 19;           // 0..5
        const int y = r - x * 19;       // 0..18
        const short* Abase = ((x < 4) ? qb_bf : tgtb) + (size_t)z * STOK;
        const short* W = sa_in_bf + (size_t)z * 196608;
        const float* bz = sa_in_b + z * 768;
        const int bm = y * 64, bn = x * 128;
        f32x4 acc[2][4] = {};

        auto stageW = [&](int k0, int buf) {
            #pragma unroll
            for (int ii = 0; ii < 4; ++ii) {
                const int c = wave * 4 + ii;
                const int n = c * 8 + nr8;
                gload_lds16(W + (size_t)(bn + n) * 256 + k0 + ((q8 ^ nr8) << 3),
                            (char*)&Bs[buf][0] + c * 1024);
            }
        };
        bhalf8 pab[2];
        auto issueA = [&](int k0) {
            #pragma unroll
            for (int ii = 0; ii < 2; ++ii) {
                const int G = t + ii * 256;
                const int m = G >> 3, g = G & 7;
                const int row = min(bm + m, NTOK - 1);
                pab[ii] = *reinterpret_cast<const bhalf8*>(
                    Abase + (size_t)row * 256 + k0 + g * 8);
            }
        };
        auto commitA = [&]() {
            #pragma unroll
            for (int ii = 0; ii < 2; ++ii) {
                const int G = t + ii * 256;
                const int m = G >> 3, g = G & 7;
                *reinterpret_cast<bhalf8*>(&As[m * 64 + ((g ^ (m & 7)) << 3)]) = pab[ii];
            }
        };
        auto compute = [&](int wbuf) {
            #pragma unroll
            for (int kf = 0; kf < 2; ++kf) {
                bhalf8 af[2], bfv[4];
                #pragma unroll
                for (int mf = 0; mf < 2; ++mf) {
                    const int m = wr * 32 + (mf << 4) + l15;
                    const int g = ((kf << 2) + l4) ^ (m & 7);
                    af[mf] = *reinterpret_cast<const bhalf8*>(&As[m * 64 + (g << 3)]);
                }
                #pragma unroll
                for (int nf = 0; nf < 4; ++nf) {
                    const int n = (wc << 6) + (nf << 4) + l15;
                    const int g = ((kf << 2) + l4) ^ (n & 7);
                    bfv[nf] = *reinterpret_cast<const bhalf8*>(&Bs[wbuf][n * 64 + (g << 3)]);
                }
                #pragma unroll
                for (int mf = 0; mf < 2; ++mf)
                    #pragma unroll
                    for (int nf = 0; nf < 4; ++nf)
                        acc[mf][nf] = __builtin_amdgcn_mfma_f32_16x16x32_bf16(
                            af[mf], bfv[nf], acc[mf][nf], 0, 0, 0);
            }
        };

        issueA(0);
        stageW(0, 0);
        commitA();
        __syncthreads();
        #pragma unroll
        for (int ks = 0; ks < 4; ++ks) {
            const int cur = ks & 1, nxt = cur ^ 1;
            if (ks + 1 < 4) {
                issueA((ks + 1) << 6);
                stageW((ks + 1) << 6, nxt);
            }
            compute(cur);
            if (ks + 1 < 4) {
                __syncthreads();
                commitA();
                __syncthreads();
            }
        }

        float* Cz = qkv + (size_t)z * 921600;
        float br[4];
        #pragma unroll
        for (int nf = 0; nf < 4; ++nf) br[nf] = bz[bn + (wc << 6) + (nf << 4) + l15];
        #pragma unroll
        for (int mf = 0; mf < 2; ++mf) {
            #pragma unroll
            for (int j = 0; j < 4; ++j) {
                const int row = bm + wr * 32 + (mf << 4) + (l4 << 2) + j;
                if (row >= NTOK) continue;
                const int colbase = bn + (wc << 6);
                #pragma unroll
                for (int nf = 0; nf < 4; ++nf)
                    Cz[(size_t)row * 768 + colbase + (nf << 4) + l15] = acc[mf][nf][j] + br[nf];
            }
        }
    }
}

// ---------------- unified bf16 MFMA GEMM (bf16 A): async gload_lds, dbuf ----------------
template<bool HASRES, bool RELU, bool OUT_BF16, int BM, int NK>
__global__ __launch_bounds__(256) void gemm_bf16(
    const short* __restrict__ Av, size_t aStrideZ, int lda,
    const short* __restrict__ Wv, size_t wStrideZ, int ldw,
    const float* __restrict__ bias, size_t biasStrideZ,
    const float* __restrict__ Res0, const float* __restrict__ Res1, int ldr,
    void* __restrict__ Cv, size_t cStrideZ, int ldc,
    int M)
{
    constexpr int MFR = BM / 32;
    constexpr int ACW = BM / 32;
    __shared__ alignas(16) short As[2][BM * 64];
    __shared__ alignas(16) short Bs[2][128 * 64];
    const int z = blockIdx.z;
    const short* W = Wv + (size_t)z * wStrideZ;
    const float* bz = bias + (size_t)z * biasStrideZ;
    const int t = threadIdx.x;
    const int wave = t >> 6, lane = t & 63;
    const int l15 = lane & 15, l4 = lane >> 4;
    const int wr = wave >> 1, wc = wave & 1;
    const int bm = blockIdx.y * BM, bn = blockIdx.x * 128;
    f32x4 acc[MFR][4] = {};

    const int nr8 = lane >> 3, q8 = lane & 7;
    auto stageW = [&](int k0, int buf) {
        #pragma unroll
        for (int i = 0; i < 4; ++i) {
            const int c = wave * 4 + i;
            const int n = c * 8 + nr8;
            gload_lds16(W + (size_t)(bn + n) * ldw + k0 + ((q8 ^ nr8) << 3),
                        (char*)&Bs[buf][0] + c * 1024);
        }
    };
    auto stageA = [&](int k0, int buf) {
        #pragma unroll
        for (int i = 0; i < ACW; ++i) {
            const int c = wave * ACW + i;
            const int m = c * 8 + nr8;
            const int row = min(bm + m, M - 1);
            gload_lds16(Av + (size_t)z * aStrideZ + (size_t)row * lda + k0 + ((q8 ^ (m & 7)) << 3),
                        (char*)&As[buf][0] + c * 1024);
        }
    };
    auto compute = [&](int buf) {
        #pragma unroll
        for (int kf = 0; kf < 2; ++kf) {
            bhalf8 af[MFR], bfv[4];
            #pragma unroll
            for (int mf = 0; mf < MFR; ++mf) {
                const int m = wr * (BM / 2) + (mf << 4) + l15;
                const int g = ((kf << 2) + l4) ^ (m & 7);
                af[mf] = *reinterpret_cast<const bhalf8*>(&As[buf][m * 64 + (g << 3)]);
            }
            #pragma unroll
            for (int nf = 0; nf < 4; ++nf) {
                const int n = (wc << 6) + (nf << 4) + l15;
                const int g = ((kf << 2) + l4) ^ (n & 7);
                bfv[nf] = *reinterpret_cast<const bhalf8*>(&Bs[buf][n * 64 + (g << 3)]);
            }
            #pragma unroll
            for (int mf = 0; mf < MFR; ++mf)
                #pragma unroll
                for (int nf = 0; nf < 4; ++nf)
                    acc[mf][nf] = __builtin_amdgcn_mfma_f32_16x16x32_bf16(
                        af[mf], bfv[nf], acc[mf][nf], 0, 0, 0);
        }
    };

    stageA(0, 0);
    stageW(0, 0);
    __syncthreads();
    #pragma unroll
    for (int ks = 0; ks < NK; ++ks) {
        const int cur = ks & 1, nxt = cur ^ 1;
        if (ks + 1 < NK) {
            stageA((ks + 1) << 6, nxt);
            stageW((ks + 1) << 6, nxt);
        }
        compute(cur);
        __syncthreads();
    }

    const float* Rz = HASRES ? (z ? Res1 : Res0) : nullptr;
    float br[4];
    #pragma unroll
    for (int nf = 0; nf < 4; ++nf) br[nf] = bz[bn + (wc << 6) + (nf << 4) + l15];
    #pragma unroll
    for (int mf = 0; mf < MFR; ++mf) {
        #pragma unroll
        for (int j = 0; j < 4; ++j) {
            const int row = bm + wr * (BM / 2) + (mf << 4) + (l4 << 2) + j;
            if (row >= M) continue;
            const int colbase = bn + (wc << 6);
            #pragma unroll
            for (int nf = 0; nf < 4; ++nf) {
                const int col = colbase + (nf << 4) + l15;
                float v = acc[mf][nf][j] + br[nf];
                if (HASRES) v += Rz[(size_t)row * ldr + col];
                if (RELU) v = fmaxf(v, 0.f);
                if (OUT_BF16)
                    ((short*)Cv + (size_t)z * cStrideZ)[(size_t)row * ldc + col] = f2bf(v);
                else
                    ((float*)Cv + (size_t)z * cStrideZ)[(size_t)row * ldc + col] = v;
            }
        }
    }
}

// ---------------- self-attention: key-parallel online softmax, bf16 out ----------------
__global__ __launch_bounds__(256) void attn2_kernel(
    const float* __restrict__ qkv_base, short* __restrict__ out_base)
{
    const float scale = 0.17677669529663687f;  // 1/sqrt(32)
    const float* qkv = qkv_base + (size_t)blockIdx.z * 921600;
    short* outp = out_base + (size_t)blockIdx.z * STOK;
    const int b = blockIdx.y >> 3, h = blockIdx.y & 7;
    const int t = threadIdx.x;
    const int ql = t & 31;
    const int kg = t >> 5;
    const int q = blockIdx.x * 32 + ql;
    const bool act = q < 300;
    const float* base = qkv + (size_t)b * 300 * 768;

    float qreg[32];
    if (act) {
        const float4* qp = reinterpret_cast<const float4*>(base + (size_t)q * 768 + h * 32);
        #pragma unroll
        for (int d4 = 0; d4 < 8; ++d4) {
            const float4 v = qp[d4];
            qreg[d4 * 4 + 0] = v.x; qreg[d4 * 4 + 1] = v.y;
            qreg[d4 * 4 + 2] = v.z; qreg[d4 * 4 + 3] = v.w;
        }
    }
    __shared__ float Ks[64][32];
    __shared__ float Vs[64][32];
    float m = -1e30f, l = 0.f, o[32];
    #pragma unroll
    for (int d = 0; d < 32; ++d) o[d] = 0.f;

    for (int k0 = 0; k0 < 300; k0 += 64) {
        const int cnt = min(64, 300 - k0);
        __syncthreads();
        for (int i = t; i < cnt * 32; i += 256) {
            const int kr = i >> 5, d = i & 31;
            Ks[kr][d] = base[(size_t)(k0 + kr) * 768 + 256 + h * 32 + d];
            Vs[kr][d] = base[(size_t)(k0 + kr) * 768 + 512 + h * 32 + d];
        }
        __syncthreads();
        if (act) {
            for (int kk = kg; kk < cnt; kk += 8) {
                const float4* krow = reinterpret_cast<const float4*>(&Ks[kk][0]);
                float s = 0.f;
                #pragma unroll
                for (int d4 = 0; d4 < 8; ++d4) {
                    const float4 kv = krow[d4];
                    s += qreg[d4 * 4 + 0] * kv.x + qreg[d4 * 4 + 1] * kv.y
                       + qreg[d4 * 4 + 2] * kv.z + qreg[d4 * 4 + 3] * kv.w;
                }
                s *= scale;
                const float4* vrow = reinterpret_cast<const float4*>(&Vs[kk][0]);
                if (s <= m) {
                    const float e = __expf(s - m);
                    l += e;
                    #pragma unroll
                    for (int d4 = 0; d4 < 8; ++d4) {
                        const float4 vv = vrow[d4];
                        o[d4 * 4 + 0] += e * vv.x; o[d4 * 4 + 1] += e * vv.y;
                        o[d4 * 4 + 2] += e * vv.z; o[d4 * 4 + 3] += e * vv.w;
                    }
                } else {
                    const float c = __expf(m - s);
                    l = l * c + 1.f;
                    #pragma unroll
                    for (int d4 = 0; d4 < 8; ++d4) {
                        const float4 vv = vrow[d4];
                        o[d4 * 4 + 0] = o[d4 * 4 + 0] * c + vv.x;
                        o[d4 * 4 + 1] = o[d4 * 4 + 1] * c + vv.y;
                        o[d4 * 4 + 2] = o[d4 * 4 + 2] * c + vv.z;
                        o[d4 * 4 + 3] = o[d4 * 4 + 3] * c + vv.w;
                    }
                    m = s;
                }
            }
        }
    }
    __shared__ float pm[32][8];
    __shared__ float pl[32][8];
    __shared__ float po[8][32][33];
    pm[ql][kg] = m; pl[ql][kg] = l;
    #pragma unroll
    for (int d = 0; d < 32; ++d) po[kg][d][ql] = o[d];
    __syncthreads();
    if (kg == 0) {
        float M = pm[ql][0];
        #pragma unroll
        for (int i = 1; i < 8; ++i) M = fmaxf(M, pm[ql][i]);
        float L = 0.f;
        #pragma unroll
        for (int i = 0; i < 8; ++i) L += pl[ql][i] * __expf(pm[ql][i] - M);
        const float invL = 1.f / L;
        #pragma unroll
        for (int i = 0; i < 8; ++i) pm[ql][i] = __expf(pm[ql][i] - M) * invL;
    }
    __syncthreads();
    if (act) {
        #pragma unroll
        for (int dd = 0; dd < 4; ++dd) {
            const int d = kg * 4 + dd;
            float v = 0.f;
            #pragma unroll
            for (int i = 0; i < 8; ++i) v += pm[ql][i] * po[i][d][ql];
            outp[((size_t)b * 300 + q) * 256 + h * 32 + d] = f2bf(v);
        }
    }
}

// ---------------- LN block-reduce body ----------------
#define LN_BODY(vexpr, widx)                                                  \
    const int row = blockIdx.x, t = threadIdx.x, z = blockIdx.y;              \
    (void)z;                                                                  \
    const int i = row * 256 + t;                                              \
    const float v = (vexpr);                                                  \
    __shared__ float r1[4], r2[4];                                            \
    float s = v;                                                              \
    _Pragma("unroll")                                                         \
    for (int o = 32; o; o >>= 1) s += __shfl_xor(s, o);                       \
    if ((t & 63) == 0) r1[t >> 6] = s;                                        \
    __syncthreads();                                                          \
    const float mean = (r1[0] + r1[1] + r1[2] + r1[3]) * (1.f / 256.f);       \
    const float dd = v - mean;                                                \
    float sq = dd * dd;                                                       \
    _Pragma("unroll")                                                         \
    for (int o = 32; o; o >>= 1) sq += __shfl_xor(sq, o);                     \
    if ((t & 63) == 0) r2[t >> 6] = sq;                                       \
    __syncthreads();                                                          \
    const float var = (r2[0] + r2[1] + r2[2] + r2[3]) * (1.f / 256.f);        \
    const float y = dd * rsqrtf(var + 1e-5f) * ln_w[(widx) * 256 + t]         \
                    + ln_b[(widx) * 256 + t];

__global__ __launch_bounds__(256) void ln2_fused(
    const float* __restrict__ presum, const float* __restrict__ pos0,
    const float* __restrict__ pos1, const float* __restrict__ ln_w,
    const float* __restrict__ ln_b, short* __restrict__ qc_bf,
    float* __restrict__ tgt2T)
{
    LN_BODY(presum[(size_t)z * STOK + i], z * 3 + 1)
    const float* pos = z ? pos1 : pos0;
    qc_bf[(size_t)z * STOK + i] = f2bf(y + pos[i]);
    if (z == 1) tgt2T[i] = y;
}

__global__ __launch_bounds__(256) void ln1_fused(
    const float* __restrict__ tgt2T, const float* __restrict__ out2,
    const float* __restrict__ out3, const float* __restrict__ ln_w,
    const float* __restrict__ ln_b, short* __restrict__ ln1b,
    float* __restrict__ ln1f)
{
    LN_BODY(tgt2T[row * 256 + t] + out2[row * 256 + t] + (z ? out3[row * 256 + t] : 0.f), z * 3 + 0)
    ln1b[(size_t)z * STOK + i] = f2bf(y);
    ln1f[(size_t)z * STOK + i] = y;
}

__global__ __launch_bounds__(256) void ln3_kernel(
    const float* __restrict__ ffny, const float* __restrict__ ln_w,
    const float* __restrict__ ln_b, float* __restrict__ o0,
    float* __restrict__ o1)
{
    LN_BODY(ffny[(size_t)z * STOK + i], z * 3 + 2)
    (z ? o1 : o0)[i] = y;
}

// ---------------- deformable sampling v3: bhalf8 (16B) gathers ----------------
// block 256 = 4 waves = 2 queries x 2 head-halves; lane = pg(2b)|h4(2b)|dl2(2b):
// pg = point group (1 point/level per lane), h = hh*4+h4, d-octet = dl2*8..dl2*8+7.
// Cross-point reduction via shfl_xor(16|32); lanes pg==0 write bhalf8.
__global__ __launch_bounds__(256) void sample_kernel(
    const short* __restrict__ valb, const float* __restrict__ oaw,
    const float* __restrict__ ref0, const float* __restrict__ ref1,
    short* __restrict__ out)
{
    const int HL[4] = {100, 50, 25, 13};
    const int WL[4] = {134, 67, 34, 17};
    const int ST[4] = {0, 13400, 16750, 17600};
    const int z = blockIdx.y;
    const int t = threadIdx.x;
    const int wave = t >> 6, lane = t & 63;
    const int qi = wave >> 1, hh = wave & 1;
    const int pg = lane >> 4;            // 0..3: one point per level
    const int h4 = (lane >> 2) & 3;
    const int dl2 = lane & 3;            // d-octet
    const int h = hh * 4 + h4;
    const int bq = blockIdx.x * 2 + qi;
    const int b = bq / 300;
    const float* op = oaw + ((size_t)z * NTOK + bq) * 384;
    const float* offp = op + h * 32;
    const float* awp  = op + 256 + h * 16;
    const float* refp = (z ? ref1 : ref0) + (size_t)bq * 8;
    const short* vb = valb + (size_t)z * MVAL * 256 + (size_t)b * LTOT_C * 256;
    const int co = h * 32 + dl2 * 8;

    float w16[16];
    float mx = -1e30f;
    #pragma unroll
    for (int i = 0; i < 16; ++i) { w16[i] = awp[i]; mx = fmaxf(mx, w16[i]); }
    float ssum = 0.f;
    #pragma unroll
    for (int i = 0; i < 16; ++i) { w16[i] = __expf(w16[i] - mx); ssum += w16[i]; }
    const float sinv = 1.f / ssum;

    float a[8] = {};
    auto tap = [&](bool cond, int ridx, float wv) {
        if (cond) {
            const bhalf8 sv = *reinterpret_cast<const bhalf8*>(vb + (size_t)ridx * 256 + co);
            #pragma unroll
            for (int dd = 0; dd < 8; ++dd) a[dd] += wv * bf2f(sv[dd]);
        }
    };
    #pragma unroll
    for (int l = 0; l < 4; ++l) {
        const int Wl = WL[l], Hl = HL[l];
        const float rx = refp[l * 2] * (float)Wl - 0.5f;
        const float ry = refp[l * 2 + 1] * (float)Hl - 0.5f;
        const float px = rx + offp[(l * 4 + pg) * 2];
        const float py = ry + offp[(l * 4 + pg) * 2 + 1];
        const float wgt = w16[l * 4 + pg] * sinv;
        const float x0f = floorf(px), y0f = floorf(py);
        const float wx = px - x0f, wy = py - y0f;
        const int x0 = (int)x0f, y0 = (int)y0f;
        const bool xa = (x0 >= 0) & (x0 < Wl);
        const bool xb = (x0 >= -1) & (x0 < Wl - 1);
        const bool ya = (y0 >= 0) & (y0 < Hl);
        const bool yb = (y0 >= -1) & (y0 < Hl - 1);
        const int rbase = ST[l] + y0 * Wl + x0;
        tap(ya & xa, rbase,          wgt * (1.f - wx) * (1.f - wy));
        tap(ya & xb, rbase + 1,      wgt * wx * (1.f - wy));
        tap(yb & xa, rbase + Wl,     wgt * (1.f - wx) * wy);
        tap(yb & xb, rbase + Wl + 1, wgt * wx * wy);
    }
    // reduce over the 4 point-groups (lane bits 4 and 5)
    #pragma unroll
    for (int dd = 0; dd < 8; ++dd) {
        a[dd] += __shfl_xor(a[dd], 16);
        a[dd] += __shfl_xor(a[dd], 32);
    }
    if (pg == 0) {
        bhalf8 o8;
        #pragma unroll
        for (int dd = 0; dd < 8; ++dd) o8[dd] = f2bf(a[dd]);
        *reinterpret_cast<bhalf8*>(&out[((size_t)z * NTOK + bq) * 256 + co]) = o8;
    }
}

extern "C" void kernel_launch(void* const* d_in, const int* in_sizes, int n_in,
                              void* d_out, int out_size, void* d_ws, size_t ws_size,
                              hipStream_t stream) {
    const float* tgt[2] = {(const float*)d_in[0], (const float*)d_in[1]};
    const float* pos[2] = {(const float*)d_in[2], (const float*)d_in[3]};
    const float* ref[2] = {(const float*)d_in[4], (const float*)d_in[5]};
    const float* src[2] = {(const float*)d_in[6], (const float*)d_in[7]};
    const float* sa_in_w  = (const float*)d_in[8];
    const float* sa_in_b  = (const float*)d_in[9];
    const float* sa_out_w = (const float*)d_in[10];
    const float* sa_out_b = (const float*)d_in[11];
    const float* ln_w = (const float*)d_in[12];
    const float* ln_b = (const float*)d_in[13];
    const float* ffn_w1 = (const float*)d_in[14];
    const float* ffn_b1 = (const float*)d_in[15];
    const float* ffn_w2 = (const float*)d_in[16];
    const float* ffn_b2 = (const float*)d_in[17];
    const float* val_w = (const float*)d_in[18];
    const float* val_b = (const float*)d_in[19];
    const float* off_w = (const float*)d_in[20];
    const float* off_b = (const float*)d_in[21];
    const float* aw_w = (const float*)d_in[22];
    const float* aw_b = (const float*)d_in[23];
    const float* cout_w = (const float*)d_in[24];
    const float* cout_b = (const float*)d_in[25];

    char* base = (char*)d_ws;
    size_t off = 0;
    auto alloc = [&](size_t bytes) -> char* {
        char* p = base + off;
        off += (bytes + 255) & ~(size_t)255;
        return p;
    };
    short* wbf   = (short*)alloc((size_t)2031616 * 2);
    float* baw   = (float*)alloc(768 * 4);
    short* qb_bf = (short*)alloc((size_t)2 * STOK * 2);
    short* tgtb  = (short*)alloc((size_t)2 * STOK * 2);
    float* qkv   = (float*)alloc((size_t)2 * 921600 * 4);
    short* attno = (short*)alloc((size_t)2 * STOK * 2);
    float* presum= (float*)alloc((size_t)2 * STOK * 4);
    short* qc_bf = (short*)alloc((size_t)2 * STOK * 2);
    float* tgt2T = (float*)alloc((size_t)STOK * 4);
    float* oawb  = (float*)alloc((size_t)2 * NTOK * 384 * 4);
    short* valb  = (short*)alloc((size_t)2 * MVAL * 256 * 2);
    short* samp  = (short*)alloc((size_t)2 * STOK * 2);
    short* ln1b  = (short*)alloc((size_t)2 * STOK * 2);
    float* ln1f  = (float*)alloc((size_t)2 * STOK * 4);
    short* ffnh  = (short*)alloc((size_t)2 * NTOK * 1024 * 2);
    float* ffny  = (float*)alloc((size_t)2 * STOK * 4);

    // weight sub-offsets (elements)
    short* sa_in_bf  = wbf + 0;        // 393216
    short* sa_out_bf = wbf + 393216;   // 131072
    short* ffn1_bf   = wbf + 524288;   // 524288
    short* ffn2_bf   = wbf + 1048576;  // 524288
    short* val_bf    = wbf + 1572864;  // 131072
    short* cout_bf   = wbf + 1703936;  // 131072
    short* oaw_bf    = wbf + 1835008;  // 196608 = 2 x (off 65536 + aw 32768)

    float* out0 = (float*)d_out;
    float* out1 = out0 + STOK;
    float* out2 = out1 + STOK;   // F_RGB = t2_RGB
    float* out3 = out2 + STOK;   // F_T

    const dim3 b256(256);

    // 1. weights -> bf16 + activation prep (combined, 12 tasks)
    PrepArgs pa;
    pa.s[0] = sa_in_w;        pa.d[0] = sa_in_bf;       pa.n[0] = 393216;
    pa.s[1] = sa_out_w;       pa.d[1] = sa_out_bf;      pa.n[1] = 131072;
    pa.s[2] = ffn_w1;         pa.d[2] = ffn1_bf;        pa.n[2] = 524288;
    pa.s[3] = ffn_w2;         pa.d[3] = ffn2_bf;        pa.n[3] = 524288;
    pa.s[4] = val_w;          pa.d[4] = val_bf;         pa.n[4] = 131072;
    pa.s[5] = cout_w;         pa.d[5] = cout_bf;        pa.n[5] = 131072;
    pa.s[6] = off_w;          pa.d[6] = oaw_bf;         pa.n[6] = 65536;
    pa.s[7] = aw_w;           pa.d[7] = oaw_bf + 65536; pa.n[7] = 32768;
    pa.s[8] = off_w + 65536;  pa.d[8] = oaw_bf + 98304; pa.n[8] = 65536;
    pa.s[9] = aw_w + 32768;   pa.d[9] = oaw_bf + 163840;pa.n[9] = 32768;
    pa.tgt0 = tgt[0]; pa.tgt1 = tgt[1]; pa.pos0 = pos[0]; pa.pos1 = pos[1];
    pa.qb_bf = qb_bf; pa.tgtb = tgtb;
    pa.off_b = off_b; pa.aw_b = aw_b; pa.baw = baw;
    prep_all<<<dim3(150, 12), b256, 0, stream>>>(pa);

    // 2. merged: in-proj (228 blocks) + value projections (4456 blocks), 40 KB LDS
    val_inproj<<<dim3(4684), b256, 0, stream>>>(
        src[1], src[0], val_bf, val_b, valb,
        qb_bf, tgtb, sa_in_bf, sa_in_b, qkv);

    // 3. attention -> attno bf16
    attn2_kernel<<<dim3(10, 32, 2), b256, 0, stream>>>(qkv, attno);

    // 4. out-proj + residual(tgt) -> presum fp32
    gemm_bf16<true, false, false, 64, 4><<<dim3(2, 19, 2), b256, 0, stream>>>(
        attno, (size_t)STOK, 256, sa_out_bf, 65536, 256, sa_out_b, 256,
        tgt[0], tgt[1], 256, presum, (size_t)STOK, 256, NTOK);

    // 5. norm2 + qc=bf16(LN+pos) + tgt2T
    ln2_fused<<<dim3(NTOK, 2), b256, 0, stream>>>(presum, pos[0], pos[1], ln_w, ln_b, qc_bf, tgt2T);

    // 6. fused offsets+aw logits (N=384) -> oawb
    gemm_bf16<false, false, false, 64, 4><<<dim3(3, 19, 2), b256, 0, stream>>>(
        qc_bf, (size_t)STOK, 256, oaw_bf, 98304, 256, baw, 384,
        nullptr, nullptr, 0, oawb, (size_t)NTOK * 384, 384, NTOK);

    // 7. sampling (fused softmax) -> samp bf16
    sample_kernel<<<dim3(600, 2), b256, 0, stream>>>(valb, oawb, ref[0], ref[1], samp);

    // 8. cout -> out2/out3 (t2_RGB / t2_T)
    gemm_bf16<false, false, false, 64, 4><<<dim3(2, 19, 2), b256, 0, stream>>>(
        samp, (size_t)STOK, 256, cout_bf, 65536, 256, cout_b, 256,
        nullptr, nullptr, 0, out2, (size_t)STOK, 256, NTOK);

    // 9. norm1 (cross residuals fused)
    ln1_fused<<<dim3(NTOK, 2), b256, 0, stream>>>(tgt2T, out2, out3, ln_w, ln_b, ln1b, ln1f);

    // 10. FFN1 (ReLU, bf16 out)
    gemm_bf16<false, true, true, 64, 4><<<dim3(8, 19, 2), b256, 0, stream>>>(
        ln1b, (size_t)STOK, 256, ffn1_bf, 262144, 256, ffn_b1, 1024,
        nullptr, nullptr, 0, ffnh, (size_t)NTOK * 1024, 1024, NTOK);

    // 11. FFN2 + residual(ln1f) -> ffny fp32
    gemm_bf16<true, false, false, 64, 16><<<dim3(2, 19, 2), b256, 0, stream>>>(
        ffnh, (size_t)NTOK * 1024, 1024, ffn2_bf, 262144, 1024, ffn_b2, 256,
        ln1f, ln1f + STOK, 256, ffny, (size_t)STOK, 256, NTOK);

    // 12. norm3 -> out0/out1
    ln3_kernel<<<dim3(NTOK, 2), b256, 0, stream>>>(ffny, ln_w, ln_b, out0, out1);
}